// Round 1
// 440.189 us; speedup vs baseline: 1.0281x; 1.0281x over previous
//
#include <hip/hip_runtime.h>
#include <math.h>

#define NPTS  8192
#define NB    2
#define NTOT  (NPTS*NB)
#define GD    60
#define NCELL (GD*GD*GD)
#define TOTC  (NB*NCELL)
#define HCELL 0.2f
#define INVH  5.0f
#define ORGN  (-6.0f)
#define NN    8192
#define SCAN_CHUNK 1024
#define NBLK_SCAN  ((TOTC + SCAN_CHUNK - 1) / SCAN_CHUNK)
#define RMAX_GRID 4   // beyond this shell radius, fall back to exact brute-force scan

// ---------------- workspace layout (bytes) ----------------
#define OFF_CNT     ((size_t)0)
#define OFF_OFFS    (OFF_CNT    + (size_t)TOTC*4)
#define OFF_CELLID  (OFF_OFFS   + (size_t)TOTC*4)
#define OFF_RANK    (OFF_CELLID + (size_t)NTOT*4)
#define OFF_SPOS    (OFF_RANK   + (size_t)NTOT*4)          // float4 * NTOT (w = origidx bits)
#define OFF_KNN     (OFF_SPOS   + (size_t)NTOT*16)         // int * NTOT*16
#define OFF_SPATIAL (OFF_KNN    + (size_t)NTOT*16*4)       // [B,4,N]
#define OFF_XT      (OFF_SPATIAL+ (size_t)NB*4*NPTS*4)     // [B,N,128]
#define OFF_MD      (OFF_XT     + (size_t)NB*128*NPTS*4)   // [B,128,N]
#define OFF_S1      (OFF_MD     + (size_t)NB*128*NPTS*4)   // [B,32,N]
#define OFF_SF      (OFF_S1     + (size_t)NB*32*NPTS*4)    // [B,64,N]
#define OFF_Y1      (OFF_SF     + (size_t)NB*64*NPTS*4)    // [B,128,N]
#define OFF_Y2      (OFF_Y1     + (size_t)NB*128*NPTS*4)   // [B,128,N]
#define OFF_A1      (OFF_Y2     + (size_t)NB*128*NPTS*4)   // [B,64,N]
#define OFF_SC      (OFF_A1     + (size_t)NB*64*NPTS*4)    // 1088 floats
#define OFF_BSUM    (OFF_SC     + (size_t)1088*4)          // NBLK_SCAN ints
#define OFF_BPRE    (OFF_BSUM   + (size_t)NBLK_SCAN*4)     // NBLK_SCAN ints

// Replicate reference arithmetic exactly (no fma contraction).
static __device__ __forceinline__ float sumsq3(float x, float y, float z) {
    return __fadd_rn(__fadd_rn(__fmul_rn(x, x), __fmul_rn(y, y)), __fmul_rn(z, z));
}
static __device__ __forceinline__ float pdist4(float qx, float qy, float qz, float qxx,
                                               float px, float py, float pz) {
    float pxx = sumsq3(px, py, pz);
    float dot = __fadd_rn(__fadd_rn(__fmul_rn(qx, px), __fmul_rn(qy, py)), __fmul_rn(qz, pz));
    return __fsub_rn(__fadd_rn(qxx, pxx), __fadd_rn(dot, dot));
}
// monotone unsigned key for float (handles tiny negative self-distance)
static __device__ __forceinline__ unsigned fkey(float f) {
    unsigned b = __float_as_uint(f);
    return b ^ ((unsigned)(((int)b) >> 31) | 0x80000000u);
}
static __device__ __forceinline__ unsigned long long shflx64(unsigned long long v, int m) {
    unsigned lo = __shfl_xor((unsigned)v, m, 64);
    unsigned hi = __shfl_xor((unsigned)(v >> 32), m, 64);
    return ((unsigned long long)hi << 32) | lo;
}

// ---------------- grid build ----------------
__global__ void cell_build(const float* __restrict__ xyz, int* __restrict__ cnt,
                           int* __restrict__ cellid, int* __restrict__ rank) {
    int t = blockIdx.x * 256 + threadIdx.x;
    if (t >= NTOT) return;
    const float* p = xyz + (size_t)t * 3;
    float x = p[0], y = p[1], z = p[2];
    int cx = min(GD - 1, max(0, (int)floorf((x - ORGN) * INVH)));
    int cy = min(GD - 1, max(0, (int)floorf((y - ORGN) * INVH)));
    int cz = min(GD - 1, max(0, (int)floorf((z - ORGN) * INVH)));
    int gcell = (t >> 13) * NCELL + (cz * GD + cy) * GD + cx;
    rank[t] = atomicAdd(&cnt[gcell], 1);
    cellid[t] = gcell;
}

// -------- hierarchical exclusive scan of cnt[TOTC] -> offs[TOTC] --------
__global__ __launch_bounds__(256) void scan_sums(const int* __restrict__ cnt, int* __restrict__ bsum) {
    __shared__ int red[256];
    int blk = blockIdx.x, t = threadIdx.x;
    int i0 = blk * SCAN_CHUNK + t * 4;
    int s = 0;
    if (i0 + 3 < TOTC) {
        int4 v = *(const int4*)(cnt + i0);
        s = v.x + v.y + v.z + v.w;
    } else {
        for (int j = 0; j < 4; ++j) if (i0 + j < TOTC) s += cnt[i0 + j];
    }
    red[t] = s;
    __syncthreads();
    for (int d = 128; d > 0; d >>= 1) {
        if (t < d) red[t] += red[t + d];
        __syncthreads();
    }
    if (t == 0) bsum[blk] = red[0];
}

__global__ __launch_bounds__(512) void scan_top(const int* __restrict__ bsum, int* __restrict__ bpre) {
    __shared__ int ps[512];
    int t = threadIdx.x;
    int v = (t < NBLK_SCAN) ? bsum[t] : 0;
    ps[t] = v;
    __syncthreads();
    for (int d = 1; d < 512; d <<= 1) {
        int u = 0;
        if (t >= d) u = ps[t - d];
        __syncthreads();
        ps[t] += u;
        __syncthreads();
    }
    if (t < NBLK_SCAN) bpre[t] = ps[t] - v;   // exclusive
}

__global__ __launch_bounds__(256) void scan_write(const int* __restrict__ cnt, const int* __restrict__ bpre,
                                                  int* __restrict__ offs) {
    __shared__ int ps[256];
    int blk = blockIdx.x, t = threadIdx.x;
    int i0 = blk * SCAN_CHUNK + t * 4;
    int a = 0, b = 0, c = 0, d = 0;
    if (i0 + 3 < TOTC) {
        int4 v = *(const int4*)(cnt + i0);
        a = v.x; b = v.y; c = v.z; d = v.w;
    } else {
        if (i0 + 0 < TOTC) a = cnt[i0 + 0];
        if (i0 + 1 < TOTC) b = cnt[i0 + 1];
        if (i0 + 2 < TOTC) c = cnt[i0 + 2];
        if (i0 + 3 < TOTC) d = cnt[i0 + 3];
    }
    int s = a + b + c + d;
    ps[t] = s;
    __syncthreads();
    for (int dd = 1; dd < 256; dd <<= 1) {
        int u = 0;
        if (t >= dd) u = ps[t - dd];
        __syncthreads();
        ps[t] += u;
        __syncthreads();
    }
    int base = bpre[blk] + ps[t] - s;
    if (i0 + 0 < TOTC) offs[i0 + 0] = base;
    if (i0 + 1 < TOTC) offs[i0 + 1] = base + a;
    if (i0 + 2 < TOTC) offs[i0 + 2] = base + a + b;
    if (i0 + 3 < TOTC) offs[i0 + 3] = base + a + b + c;
}

__global__ void scatter_k(const float* __restrict__ xyz, const int* __restrict__ cellid,
                          const int* __restrict__ rank, const int* __restrict__ offs,
                          float4* __restrict__ spos) {
    int t = blockIdx.x * 256 + threadIdx.x;
    if (t >= NTOT) return;
    const float* p = xyz + (size_t)t * 3;
    float x = p[0], y = p[1], z = p[2];
    int pos = offs[cellid[t]] + rank[t];
    spos[pos] = make_float4(x, y, z, __int_as_float(t & (NPTS - 1)));
}

// decode u-th cell of Chebyshev shell R (R>=1); S(R)=24R^2+2
static __device__ __forceinline__ void shell_decode(int R, int u, int& dx, int& dy, int& dz) {
    int L = 2 * R + 1, P = L * L;
    if (u < 2 * P) {
        int v = (u < P) ? u : u - P;
        dz = (u < P) ? -R : R;
        dx = v % L - R;
        dy = v / L - R;
    } else {
        int w = u - 2 * P;
        int ring = w / (8 * R);
        int p = w - ring * 8 * R;
        dz = ring - (R - 1);
        if (p < 2 * R)      { dx = p - R;            dy = -R; }
        else if (p < 4 * R) { dx = R;                dy = p - 3 * R; }
        else if (p < 6 * R) { dx = 5 * R - p;        dy = R; }
        else                { dx = -R;               dy = 7 * R - p; }
    }
}

// ---------------- exact KNN: one wave per query ----------------
// R7 change: hybrid tail handling. The Gaussian point cloud has outliers whose
// 16-NN radius needs shells up to R~18 — O((2R+1)^3) mostly-empty cell scans,
// 100+ µs for a single wave (the whole kernel's tail). Cap the shell scan at
// RMAX_GRID; any query not satisfying the (unchanged, proven) margin stop-count
// by then RESETS its candidate buffer and brute-force scans all NPTS points of
// its batch, coalesced (lane + 64*i). Exactness: brute path sees every point
// exactly once, same key packing (dist,origidx,slot) -> same ordering and
// tie-break as the reference's stable top_k; per-lane 16-smallest-with-drop-max
// union contains the global top-16 as before. Everything else = R6 verbatim.
__global__ __launch_bounds__(256, 4) void knn_kernel(const float4* __restrict__ spos,
                                                     const int* __restrict__ cnt,
                                                     const int* __restrict__ offs,
                                                     int* __restrict__ knn,
                                                     float* __restrict__ spatial) {
    __shared__ unsigned long long buf[4][16][64];
    int lane = threadIdx.x & 63;
    int wv   = threadIdx.x >> 6;
    int s    = blockIdx.x * 4 + wv;       // query slot in sorted order
    float4 q = spos[s];
    float qx = q.x, qy = q.y, qz = q.z;
    float qxx = sumsq3(qx, qy, qz);
    int b  = s >> 13;
    int nq = __float_as_int(q.w);
    int cx = min(GD - 1, max(0, (int)floorf((qx - ORGN) * INVH)));
    int cy = min(GD - 1, max(0, (int)floorf((qy - ORGN) * INVH)));
    int cz = min(GD - 1, max(0, (int)floorf((qz - ORGN) * INVH)));
    const int* cb = cnt  + b * NCELL;
    const int* ob = offs + b * NCELL;     // offs is a GLOBAL scan; base below is a global slot

    unsigned long long* mybuf = &buf[wv][0][lane];   // element j at mybuf[j*64]
    unsigned long long minkey = ~0ULL;
    unsigned long long maxkey = 0;
    int nbuf = 0;

    int R = 0;
    int brute = 0;
    while (true) {
        int S = (R == 0) ? 1 : 24 * R * R + 2;
        for (int u0 = 0; u0 < S; u0 += 64) {
            int u = u0 + lane;
            int num = 0, base = 0;
            if (u < S) {
                int dx = 0, dy = 0, dz = 0;
                if (R > 0) shell_decode(R, u, dx, dy, dz);
                int xc = cx + dx, yc = cy + dy, zc = cz + dz;
                if ((unsigned)xc < GD && (unsigned)yc < GD && (unsigned)zc < GD) {
                    int cell = (zc * GD + yc) * GD + xc;
                    num  = cb[cell];
                    base = ob[cell];
                }
            }
            for (int i = 0; i < num; ++i) {
                float4 p = spos[base + i];          // base is global (includes batch offset)
                float d = pdist4(qx, qy, qz, qxx, p.x, p.y, p.z);
                int oi = __float_as_int(p.w);
                unsigned long long key = ((unsigned long long)fkey(d) << 27)
                                       | ((unsigned long long)(unsigned)oi << 14)
                                       | (unsigned)(base + i);
                if (nbuf < 16) {
                    mybuf[(size_t)nbuf * 64] = key;
                    ++nbuf;
                    minkey = (key < minkey) ? key : minkey;
                    maxkey = (key > maxkey) ? key : maxkey;
                } else if (key < maxkey) {
                    // rare: buffer full — replace current max, keep 16 smallest
                    unsigned long long vmax = 0, v2 = 0;
                    int pmax = 0;
                    #pragma unroll
                    for (int j = 0; j < 16; ++j) {
                        unsigned long long v = mybuf[(size_t)j * 64];
                        if (v > vmax) { v2 = vmax; vmax = v; pmax = j; }
                        else if (v > v2) { v2 = v; }
                    }
                    mybuf[(size_t)pmax * 64] = key;
                    maxkey = (key > v2) ? key : v2;
                    minkey = (key < minkey) ? key : minkey;
                }
            }
        }
        // stop: >=16 candidates strictly inside the exact box-face margin (R5-proven).
        float mlx = qx - (ORGN + (float)(cx - R) * HCELL);
        float mhx = (ORGN + (float)(cx + R + 1) * HCELL) - qx;
        float mly = qy - (ORGN + (float)(cy - R) * HCELL);
        float mhy = (ORGN + (float)(cy + R + 1) * HCELL) - qy;
        float mlz = qz - (ORGN + (float)(cz - R) * HCELL);
        float mhz = (ORGN + (float)(cz + R + 1) * HCELL) - qz;
        float margin = fminf(fminf(fminf(mlx, mhx), fminf(mly, mhy)), fminf(mlz, mhz));
        float thr = margin * margin - 1e-4f;   // shave covers fp cancellation in pdist4
        unsigned long long tkey = ((unsigned long long)(fkey(thr) + 1u)) << 27;
        int c = 0;
        for (int j = 0; j < nbuf; ++j) c += (mybuf[(size_t)j * 64] < tkey) ? 1 : 0;
        for (int o = 32; o > 0; o >>= 1) c += __shfl_xor(c, o, 64);
        if (c >= 16) break;
        if (R >= RMAX_GRID) { brute = 1; break; }
        ++R;
    }

    if (brute) {
        // exact fallback: rescan ALL points of this batch, coalesced.
        // Reset buffer so every point is seen exactly once (no duplicates).
        nbuf = 0; minkey = ~0ULL; maxkey = 0;
        int sbase = b << 13;
        for (int i = lane; i < NPTS; i += 64) {
            float4 p = spos[sbase + i];
            float d = pdist4(qx, qy, qz, qxx, p.x, p.y, p.z);
            int oi = __float_as_int(p.w);
            unsigned long long key = ((unsigned long long)fkey(d) << 27)
                                   | ((unsigned long long)(unsigned)oi << 14)
                                   | (unsigned)(sbase + i);
            if (nbuf < 16) {
                mybuf[(size_t)nbuf * 64] = key;
                ++nbuf;
                minkey = (key < minkey) ? key : minkey;
                maxkey = (key > maxkey) ? key : maxkey;
            } else if (key < maxkey) {
                unsigned long long vmax = 0, v2 = 0;
                int pmax = 0;
                #pragma unroll
                for (int j = 0; j < 16; ++j) {
                    unsigned long long v = mybuf[(size_t)j * 64];
                    if (v > vmax) { v2 = vmax; vmax = v; pmax = j; }
                    else if (v > v2) { v2 = v; }
                }
                mybuf[(size_t)pmax * 64] = key;
                maxkey = (key > v2) ? key : v2;
                minkey = (key < minkey) ? key : minkey;
            }
        }
    }

    // exact global top-16: 16 rounds of wave-wide u64 argmin over cached lane minima
    unsigned long long keep = ~0ULL;
    for (int k = 0; k < 16; ++k) {
        unsigned long long m = minkey;
        for (int o = 32; o > 0; o >>= 1) {
            unsigned long long pv = shflx64(m, o);
            m = (pv < m) ? pv : m;
        }
        unsigned long long bal = __ballot(minkey == m);
        int wl = __ffsll((long long)bal) - 1;
        if (lane == wl) {
            int pos = 0;
            for (int j = 0; j < nbuf; ++j) if (mybuf[(size_t)j * 64] == m) pos = j;
            --nbuf;
            mybuf[(size_t)pos * 64] = mybuf[(size_t)nbuf * 64];
            unsigned long long nm = ~0ULL;
            for (int j = 0; j < nbuf; ++j) {
                unsigned long long v = mybuf[(size_t)j * 64];
                nm = (v < nm) ? v : nm;
            }
            minkey = nm;
        }
        if (lane == k) keep = m;
    }

    float rx = 0.f, ry = 0.f, rz = 0.f, rd = 0.f;
    if (lane < 16) {
        int sp = (int)(keep & 0x3FFFu);
        int oi = (int)((keep >> 14) & 0x1FFFu);
        float4 p = spos[sp];
        rx = p.x - qx; ry = p.y - qy; rz = p.z - qz;
        rd = sqrtf(__fadd_rn(__fadd_rn(__fmul_rn(rx, rx), __fmul_rn(ry, ry)), __fmul_rn(rz, rz)));
        knn[(((size_t)b << 13) + nq) * 16 + lane] = oi;
    }
    for (int o = 8; o > 0; o >>= 1) {
        rx += __shfl_xor(rx, o, 64);
        ry += __shfl_xor(ry, o, 64);
        rz += __shfl_xor(rz, o, 64);
        rd += __shfl_xor(rd, o, 64);
    }
    if (lane == 0) {
        const float inv16 = 0.0625f;
        spatial[((size_t)b * 4 + 0) * NPTS + nq] = rx * inv16;
        spatial[((size_t)b * 4 + 1) * NPTS + nq] = ry * inv16;
        spatial[((size_t)b * 4 + 2) * NPTS + nq] = rz * inv16;
        spatial[((size_t)b * 4 + 3) * NPTS + nq] = rd * inv16;
    }
}

// ---------------- x[B,C,N] -> xT[B,N,C] ----------------
__global__ void transpose_k(const float* __restrict__ x, float* __restrict__ xT) {
    __shared__ float tl[32][33];
    int b = blockIdx.z;
    int n0 = blockIdx.x * 32, c0 = blockIdx.y * 32;
    int tx = threadIdx.x, ty = threadIdx.y;
    const float* xb = x + (size_t)b * 128 * NN;
    float* xtb = xT + (size_t)b * NN * 128;
    for (int i = 0; i < 32; i += 8) tl[ty + i][tx] = xb[(size_t)(c0 + ty + i) * NN + n0 + tx];
    __syncthreads();
    for (int i = 0; i < 32; i += 8) xtb[(size_t)(n0 + ty + i) * 128 + c0 + tx] = tl[tx][ty + i];
}

// ---------------- max_k(x[:,idx_k]) - x  -> md[B,128,N] ----------------
__global__ __launch_bounds__(256) void md_k(const float* __restrict__ xT,
                                            const int* __restrict__ knn,
                                            float* __restrict__ md) {
    __shared__ int ki[8][16];
    __shared__ float smd[8][132];
    int b = blockIdx.y;
    int n0 = blockIdx.x * 8;
    int tid = threadIdx.x;
    if (tid < 128) ki[tid >> 4][tid & 15] = knn[(((size_t)b << 13) + n0 + (tid >> 4)) * 16 + (tid & 15)];
    __syncthreads();
    int nl = tid >> 5;
    int c4 = (tid & 31) * 4;
    const float* xb = xT + (size_t)b * NPTS * 128;
    float4 m = make_float4(-3.0e38f, -3.0e38f, -3.0e38f, -3.0e38f);
    #pragma unroll
    for (int k = 0; k < 16; ++k) {
        const float4 g = *(const float4*)(xb + (size_t)ki[nl][k] * 128 + c4);
        m.x = fmaxf(m.x, g.x); m.y = fmaxf(m.y, g.y); m.z = fmaxf(m.z, g.z); m.w = fmaxf(m.w, g.w);
    }
    const float4 own = *(const float4*)(xb + (size_t)(n0 + nl) * 128 + c4);
    m.x -= own.x; m.y -= own.y; m.z -= own.z; m.w -= own.w;
    *(float4*)(&smd[nl][c4]) = m;
    __syncthreads();
    for (int r = 0; r < 4; ++r) {
        int c = (tid >> 3) + 32 * r;
        int n2 = tid & 7;
        md[((size_t)b * 128 + c) * NN + n0 + n2] = smd[n2][c];
    }
}

// ---------------- fold conv-bias + BN into per-channel scale/shift ----------------
__global__ void prep_k(const float* bb1, const float* g1, const float* be1, const float* m1, const float* v1,
                       const float* bb2, const float* g2, const float* be2, const float* m2, const float* v2,
                       const float* sb1, const float* gs,  const float* bes, const float* ms, const float* vs,
                       const float* sb2,
                       const float* ab1, const float* ga,  const float* bea, const float* ma, const float* va,
                       const float* ab2, float* sc) {
    int t = threadIdx.x;
    if (t < 128) {
        float i1 = g1[t] / sqrtf(v1[t] + 1e-5f);
        sc[t] = i1;        sc[128 + t] = bb1[t] * i1 + be1[t] - m1[t] * i1;
        float i2 = g2[t] / sqrtf(v2[t] + 1e-5f);
        sc[256 + t] = i2;  sc[384 + t] = bb2[t] * i2 + be2[t] - m2[t] * i2;
        sc[832 + t] = 1.0f; sc[960 + t] = ab2[t];
    }
    if (t < 32) {
        float is = gs[t] / sqrtf(vs[t] + 1e-5f);
        sc[512 + t] = is;  sc[544 + t] = sb1[t] * is + bes[t] - ms[t] * is;
    }
    if (t < 64) {
        sc[576 + t] = 1.0f; sc[640 + t] = sb2[t];
        float ia = ga[t] / sqrtf(va[t] + 1e-5f);
        sc[704 + t] = ia;  sc[768 + t] = ab1[t] * ia + bea[t] - ma[t] * ia;
    }
}

// ---------------- generic 1x1-conv (+folded BN, activation) ----------------
// ACT: 0=none, 1=relu, 2=sigmoid + fused "dout = x + y2*attn"
template <int O, int K, int TILE_N, int SPLIT, int ACT>
__global__ __launch_bounds__(256) void conv_bn(const float* __restrict__ srcA,
                                               const float* __restrict__ srcB,
                                               const float* __restrict__ W,
                                               const float* __restrict__ scale,
                                               const float* __restrict__ shift,
                                               float* __restrict__ out,
                                               const float* __restrict__ resx,
                                               const float* __restrict__ y2,
                                               float* __restrict__ dout) {
    constexpr int KC  = (K < 64) ? K : 64;
    constexpr int NT4 = TILE_N / 4;
    constexpr int O4  = O / 4;
    static_assert(NT4 * O4 == 256, "thread mapping");
    __shared__ float wT[KC][O + 4];
    __shared__ float inT[KC][TILE_N];
    int tid = threadIdx.x;
    int b = blockIdx.z;
    int n0 = blockIdx.x * TILE_N;
    int n_thr = tid % NT4;          // n fastest -> coalesced stores
    int o_thr = tid / NT4;
    float acc[4][4] = {{0.f, 0.f, 0.f, 0.f}, {0.f, 0.f, 0.f, 0.f}, {0.f, 0.f, 0.f, 0.f}, {0.f, 0.f, 0.f, 0.f}};

    for (int k0 = 0; k0 < K; k0 += KC) {
        for (int idx = tid; idx < KC * O; idx += 256) {
            int cc = idx % KC;
            int o  = idx / KC;
            wT[cc][o] = W[(size_t)o * K + k0 + cc];
        }
        for (int idx = tid; idx < KC * NT4; idx += 256) {
            int cc = idx / NT4;
            int nf = idx % NT4;
            int cg = k0 + cc;
            const float* src = (cg < SPLIT)
                ? (srcA + ((size_t)b * SPLIT + cg) * NN)
                : (srcB + ((size_t)b * (K - SPLIT) + (cg - SPLIT)) * NN);
            *(float4*)(&inT[cc][nf * 4]) = *(const float4*)(src + n0 + nf * 4);
        }
        __syncthreads();
        #pragma unroll 8
        for (int c = 0; c < KC; ++c) {
            float4 wv = *(const float4*)(&wT[c][o_thr * 4]);
            float4 iv = *(const float4*)(&inT[c][n_thr * 4]);
            acc[0][0] = fmaf(wv.x, iv.x, acc[0][0]); acc[0][1] = fmaf(wv.x, iv.y, acc[0][1]);
            acc[0][2] = fmaf(wv.x, iv.z, acc[0][2]); acc[0][3] = fmaf(wv.x, iv.w, acc[0][3]);
            acc[1][0] = fmaf(wv.y, iv.x, acc[1][0]); acc[1][1] = fmaf(wv.y, iv.y, acc[1][1]);
            acc[1][2] = fmaf(wv.y, iv.z, acc[1][2]); acc[1][3] = fmaf(wv.y, iv.w, acc[1][3]);
            acc[2][0] = fmaf(wv.z, iv.x, acc[2][0]); acc[2][1] = fmaf(wv.z, iv.y, acc[2][1]);
            acc[2][2] = fmaf(wv.z, iv.z, acc[2][2]); acc[2][3] = fmaf(wv.z, iv.w, acc[2][3]);
            acc[3][0] = fmaf(wv.w, iv.x, acc[3][0]); acc[3][1] = fmaf(wv.w, iv.y, acc[3][1]);
            acc[3][2] = fmaf(wv.w, iv.z, acc[3][2]); acc[3][3] = fmaf(wv.w, iv.w, acc[3][3]);
        }
        __syncthreads();
    }
    #pragma unroll
    for (int j = 0; j < 4; ++j) {
        int o = o_thr * 4 + j;
        float scv = scale[o], shv = shift[o];
        float4 v;
        v.x = fmaf(acc[j][0], scv, shv);
        v.y = fmaf(acc[j][1], scv, shv);
        v.z = fmaf(acc[j][2], scv, shv);
        v.w = fmaf(acc[j][3], scv, shv);
        size_t obase = ((size_t)b * O + o) * NN + n0 + n_thr * 4;
        if (ACT == 1) {
            v.x = fmaxf(v.x, 0.f); v.y = fmaxf(v.y, 0.f); v.z = fmaxf(v.z, 0.f); v.w = fmaxf(v.w, 0.f);
            *(float4*)(out + obase) = v;
        } else if (ACT == 2) {
            float4 xr = *(const float4*)(resx + obase);
            float4 yr = *(const float4*)(y2 + obase);
            v.x = xr.x + yr.x / (1.f + __expf(-v.x));
            v.y = xr.y + yr.y / (1.f + __expf(-v.y));
            v.z = xr.z + yr.z / (1.f + __expf(-v.z));
            v.w = xr.w + yr.w / (1.f + __expf(-v.w));
            *(float4*)(dout + obase) = v;
        } else {
            *(float4*)(out + obase) = v;
        }
    }
}

extern "C" void kernel_launch(void* const* d_in, const int* in_sizes, int n_in,
                              void* d_out, int out_size, void* d_ws, size_t ws_size,
                              hipStream_t stream) {
    (void)in_sizes; (void)n_in; (void)out_size; (void)ws_size;
    const float* x    = (const float*)d_in[0];
    const float* xyz  = (const float*)d_in[1];
    const float* bw1  = (const float*)d_in[2];
    const float* bb1  = (const float*)d_in[3];
    const float* bn1g = (const float*)d_in[4];
    const float* bn1b = (const float*)d_in[5];
    const float* bn1m = (const float*)d_in[6];
    const float* bn1v = (const float*)d_in[7];
    const float* bw2  = (const float*)d_in[8];
    const float* bb2  = (const float*)d_in[9];
    const float* bn2g = (const float*)d_in[10];
    const float* bn2b = (const float*)d_in[11];
    const float* bn2m = (const float*)d_in[12];
    const float* bn2v = (const float*)d_in[13];
    const float* sw1  = (const float*)d_in[14];
    const float* sb1  = (const float*)d_in[15];
    const float* sbng = (const float*)d_in[16];
    const float* sbnb = (const float*)d_in[17];
    const float* sbnm = (const float*)d_in[18];
    const float* sbnv = (const float*)d_in[19];
    const float* sw2  = (const float*)d_in[20];
    const float* sb2  = (const float*)d_in[21];
    const float* aw1  = (const float*)d_in[22];
    const float* ab1  = (const float*)d_in[23];
    const float* abng = (const float*)d_in[24];
    const float* abnb = (const float*)d_in[25];
    const float* abnm = (const float*)d_in[26];
    const float* abnv = (const float*)d_in[27];
    const float* aw2  = (const float*)d_in[28];
    const float* ab2  = (const float*)d_in[29];

    char* ws = (char*)d_ws;
    int*    cnt    = (int*)(ws + OFF_CNT);
    int*    offs   = (int*)(ws + OFF_OFFS);
    int*    cellid = (int*)(ws + OFF_CELLID);
    int*    rank   = (int*)(ws + OFF_RANK);
    float4* spos   = (float4*)(ws + OFF_SPOS);
    int*    knn    = (int*)(ws + OFF_KNN);
    float*  spat   = (float*)(ws + OFF_SPATIAL);
    float*  xT     = (float*)(ws + OFF_XT);
    float*  md     = (float*)(ws + OFF_MD);
    float*  s1b    = (float*)(ws + OFF_S1);
    float*  sfb    = (float*)(ws + OFF_SF);
    float*  y1b    = (float*)(ws + OFF_Y1);
    float*  y2b    = (float*)(ws + OFF_Y2);
    float*  a1b    = (float*)(ws + OFF_A1);
    float*  sc     = (float*)(ws + OFF_SC);
    int*    bsum   = (int*)(ws + OFF_BSUM);
    int*    bpre   = (int*)(ws + OFF_BPRE);
    float*  dout   = (float*)d_out;

    hipMemsetAsync(cnt, 0, (size_t)TOTC * 4, stream);
    cell_build<<<dim3((NTOT + 255) / 256), 256, 0, stream>>>(xyz, cnt, cellid, rank);
    scan_sums<<<dim3(NBLK_SCAN), 256, 0, stream>>>(cnt, bsum);
    scan_top<<<dim3(1), 512, 0, stream>>>(bsum, bpre);
    scan_write<<<dim3(NBLK_SCAN), 256, 0, stream>>>(cnt, bpre, offs);
    scatter_k<<<dim3((NTOT + 255) / 256), 256, 0, stream>>>(xyz, cellid, rank, offs, spos);
    knn_kernel<<<dim3(NTOT / 4), 256, 0, stream>>>(spos, cnt, offs, knn, spat);
    transpose_k<<<dim3(NPTS / 32, 128 / 32, NB), dim3(32, 8), 0, stream>>>(x, xT);
    md_k<<<dim3(NPTS / 8, NB), 256, 0, stream>>>(xT, knn, md);
    prep_k<<<1, 128, 0, stream>>>(bb1, bn1g, bn1b, bn1m, bn1v,
                                  bb2, bn2g, bn2b, bn2m, bn2v,
                                  sb1, sbng, sbnb, sbnm, sbnv,
                                  sb2,
                                  ab1, abng, abnb, abnm, abnv,
                                  ab2, sc);
    // spatial MLP: 4->32 (bn,relu), 32->64
    conv_bn<32, 4, 128, 4, 1><<<dim3(NPTS / 128, 1, NB), 256, 0, stream>>>(
        spat, spat, sw1, sc + 512, sc + 544, s1b, nullptr, nullptr, nullptr);
    conv_bn<64, 32, 64, 32, 0><<<dim3(NPTS / 64, 1, NB), 256, 0, stream>>>(
        s1b, s1b, sw2, sc + 576, sc + 640, sfb, nullptr, nullptr, nullptr);
    // boundary net: [x;md] 256->128 (bn,relu), 128->128 (bn,relu)
    conv_bn<128, 256, 32, 128, 1><<<dim3(NPTS / 32, 1, NB), 256, 0, stream>>>(
        x, md, bw1, sc + 0, sc + 128, y1b, nullptr, nullptr, nullptr);
    conv_bn<128, 128, 32, 128, 1><<<dim3(NPTS / 32, 1, NB), 256, 0, stream>>>(
        y1b, y1b, bw2, sc + 256, sc + 384, y2b, nullptr, nullptr, nullptr);
    // attention: [x;sfeat] 192->64 (bn,relu), 64->128 sigmoid + final fuse
    conv_bn<64, 192, 64, 128, 1><<<dim3(NPTS / 64, 1, NB), 256, 0, stream>>>(
        x, sfb, aw1, sc + 704, sc + 768, a1b, nullptr, nullptr, nullptr);
    conv_bn<128, 64, 32, 64, 2><<<dim3(NPTS / 32, 1, NB), 256, 0, stream>>>(
        a1b, a1b, aw2, sc + 832, sc + 960, dout, x, y2b, dout);
}

// Round 2
// 427.278 us; speedup vs baseline: 1.0592x; 1.0302x over previous
//
#include <hip/hip_runtime.h>
#include <math.h>

#define NPTS  8192
#define NB    2
#define NTOT  (NPTS*NB)
#define GD    60
#define NCELL (GD*GD*GD)
#define TOTC  (NB*NCELL)
#define HCELL 0.2f
#define INVH  5.0f
#define ORGN  (-6.0f)
#define NN    8192
#define SCAN_CHUNK 1024
#define NBLK_SCAN  ((TOTC + SCAN_CHUNK - 1) / SCAN_CHUNK)
#define RMAX_GRID 4   // beyond this shell radius, fall back to exact brute-force scan
#define LIST_CAP 512  // per-wave expansion list (ints); reused as sel keys (256 u64)
#define CSEL_CAP 192  // rank-select path cap; larger falls back to 16-round extraction

// ---------------- workspace layout (bytes) ----------------
#define OFF_CNT     ((size_t)0)
#define OFF_OFFS    (OFF_CNT    + (size_t)TOTC*4)
#define OFF_CELLID  (OFF_OFFS   + (size_t)TOTC*4)
#define OFF_RANK    (OFF_CELLID + (size_t)NTOT*4)
#define OFF_SPOS    (OFF_RANK   + (size_t)NTOT*4)          // float4 * NTOT (w = origidx bits)
#define OFF_KNN     (OFF_SPOS   + (size_t)NTOT*16)         // int * NTOT*16
#define OFF_SPATIAL (OFF_KNN    + (size_t)NTOT*16*4)       // [B,4,N]
#define OFF_XT      (OFF_SPATIAL+ (size_t)NB*4*NPTS*4)     // [B,N,128]
#define OFF_MD      (OFF_XT     + (size_t)NB*128*NPTS*4)   // [B,128,N]
#define OFF_S1      (OFF_MD     + (size_t)NB*128*NPTS*4)   // [B,32,N]
#define OFF_SF      (OFF_S1     + (size_t)NB*32*NPTS*4)    // [B,64,N]
#define OFF_Y1      (OFF_SF     + (size_t)NB*64*NPTS*4)    // [B,128,N]
#define OFF_Y2      (OFF_Y1     + (size_t)NB*128*NPTS*4)   // [B,128,N]
#define OFF_A1      (OFF_Y2     + (size_t)NB*128*NPTS*4)   // [B,64,N]
#define OFF_SC      (OFF_A1     + (size_t)NB*64*NPTS*4)    // 1088 floats
#define OFF_BSUM    (OFF_SC     + (size_t)1088*4)          // NBLK_SCAN ints
#define OFF_BPRE    (OFF_BSUM   + (size_t)NBLK_SCAN*4)     // NBLK_SCAN ints

// Replicate reference arithmetic exactly (no fma contraction).
static __device__ __forceinline__ float sumsq3(float x, float y, float z) {
    return __fadd_rn(__fadd_rn(__fmul_rn(x, x), __fmul_rn(y, y)), __fmul_rn(z, z));
}
static __device__ __forceinline__ float pdist4(float qx, float qy, float qz, float qxx,
                                               float px, float py, float pz) {
    float pxx = sumsq3(px, py, pz);
    float dot = __fadd_rn(__fadd_rn(__fmul_rn(qx, px), __fmul_rn(qy, py)), __fmul_rn(qz, pz));
    return __fsub_rn(__fadd_rn(qxx, pxx), __fadd_rn(dot, dot));
}
// monotone unsigned key for float (handles tiny negative self-distance)
static __device__ __forceinline__ unsigned fkey(float f) {
    unsigned b = __float_as_uint(f);
    return b ^ ((unsigned)(((int)b) >> 31) | 0x80000000u);
}
static __device__ __forceinline__ unsigned long long shflx64(unsigned long long v, int m) {
    unsigned lo = __shfl_xor((unsigned)v, m, 64);
    unsigned hi = __shfl_xor((unsigned)(v >> 32), m, 64);
    return ((unsigned long long)hi << 32) | lo;
}
// inclusive wave prefix-sum (all 64 lanes active)
static __device__ __forceinline__ int wave_scan_incl(int v, int lane) {
    #pragma unroll
    for (int d = 1; d < 64; d <<= 1) {
        int u = __shfl_up(v, d, 64);
        v += (lane >= d) ? u : 0;
    }
    return v;
}

// ---------------- grid build ----------------
__global__ void cell_build(const float* __restrict__ xyz, int* __restrict__ cnt,
                           int* __restrict__ cellid, int* __restrict__ rank) {
    int t = blockIdx.x * 256 + threadIdx.x;
    if (t >= NTOT) return;
    const float* p = xyz + (size_t)t * 3;
    float x = p[0], y = p[1], z = p[2];
    int cx = min(GD - 1, max(0, (int)floorf((x - ORGN) * INVH)));
    int cy = min(GD - 1, max(0, (int)floorf((y - ORGN) * INVH)));
    int cz = min(GD - 1, max(0, (int)floorf((z - ORGN) * INVH)));
    int gcell = (t >> 13) * NCELL + (cz * GD + cy) * GD + cx;
    rank[t] = atomicAdd(&cnt[gcell], 1);
    cellid[t] = gcell;
}

// -------- hierarchical exclusive scan of cnt[TOTC] -> offs[TOTC] --------
__global__ __launch_bounds__(256) void scan_sums(const int* __restrict__ cnt, int* __restrict__ bsum) {
    __shared__ int red[256];
    int blk = blockIdx.x, t = threadIdx.x;
    int i0 = blk * SCAN_CHUNK + t * 4;
    int s = 0;
    if (i0 + 3 < TOTC) {
        int4 v = *(const int4*)(cnt + i0);
        s = v.x + v.y + v.z + v.w;
    } else {
        for (int j = 0; j < 4; ++j) if (i0 + j < TOTC) s += cnt[i0 + j];
    }
    red[t] = s;
    __syncthreads();
    for (int d = 128; d > 0; d >>= 1) {
        if (t < d) red[t] += red[t + d];
        __syncthreads();
    }
    if (t == 0) bsum[blk] = red[0];
}

__global__ __launch_bounds__(512) void scan_top(const int* __restrict__ bsum, int* __restrict__ bpre) {
    __shared__ int ps[512];
    int t = threadIdx.x;
    int v = (t < NBLK_SCAN) ? bsum[t] : 0;
    ps[t] = v;
    __syncthreads();
    for (int d = 1; d < 512; d <<= 1) {
        int u = 0;
        if (t >= d) u = ps[t - d];
        __syncthreads();
        ps[t] += u;
        __syncthreads();
    }
    if (t < NBLK_SCAN) bpre[t] = ps[t] - v;   // exclusive
}

__global__ __launch_bounds__(256) void scan_write(const int* __restrict__ cnt, const int* __restrict__ bpre,
                                                  int* __restrict__ offs) {
    __shared__ int ps[256];
    int blk = blockIdx.x, t = threadIdx.x;
    int i0 = blk * SCAN_CHUNK + t * 4;
    int a = 0, b = 0, c = 0, d = 0;
    if (i0 + 3 < TOTC) {
        int4 v = *(const int4*)(cnt + i0);
        a = v.x; b = v.y; c = v.z; d = v.w;
    } else {
        if (i0 + 0 < TOTC) a = cnt[i0 + 0];
        if (i0 + 1 < TOTC) b = cnt[i0 + 1];
        if (i0 + 2 < TOTC) c = cnt[i0 + 2];
        if (i0 + 3 < TOTC) d = cnt[i0 + 3];
    }
    int s = a + b + c + d;
    ps[t] = s;
    __syncthreads();
    for (int dd = 1; dd < 256; dd <<= 1) {
        int u = 0;
        if (t >= dd) u = ps[t - dd];
        __syncthreads();
        ps[t] += u;
        __syncthreads();
    }
    int base = bpre[blk] + ps[t] - s;
    if (i0 + 0 < TOTC) offs[i0 + 0] = base;
    if (i0 + 1 < TOTC) offs[i0 + 1] = base + a;
    if (i0 + 2 < TOTC) offs[i0 + 2] = base + a + b;
    if (i0 + 3 < TOTC) offs[i0 + 3] = base + a + b + c;
}

__global__ void scatter_k(const float* __restrict__ xyz, const int* __restrict__ cellid,
                          const int* __restrict__ rank, const int* __restrict__ offs,
                          float4* __restrict__ spos) {
    int t = blockIdx.x * 256 + threadIdx.x;
    if (t >= NTOT) return;
    const float* p = xyz + (size_t)t * 3;
    float x = p[0], y = p[1], z = p[2];
    int pos = offs[cellid[t]] + rank[t];
    spos[pos] = make_float4(x, y, z, __int_as_float(t & (NPTS - 1)));
}

// decode u-th cell of Chebyshev shell R (R>=1); S(R)=24R^2+2
static __device__ __forceinline__ void shell_decode(int R, int u, int& dx, int& dy, int& dz) {
    int L = 2 * R + 1, P = L * L;
    if (u < 2 * P) {
        int v = (u < P) ? u : u - P;
        dz = (u < P) ? -R : R;
        dx = v % L - R;
        dy = v / L - R;
    } else {
        int w = u - 2 * P;
        int ring = w / (8 * R);
        int p = w - ring * 8 * R;
        dz = ring - (R - 1);
        if (p < 2 * R)      { dx = p - R;            dy = -R; }
        else if (p < 4 * R) { dx = R;                dy = p - 3 * R; }
        else if (p < 6 * R) { dx = 5 * R - p;        dy = R; }
        else                { dx = -R;               dy = 7 * R - p; }
    }
}

// ---------------- exact KNN: one wave per query ----------------
// R8 changes (shells/stop/brute = R7 verbatim):
// (a) balanced candidate processing: per 64-cell shell batch, wave-prefix-scan
//     per-lane cell counts, expand the concatenated slot list into LDS
//     (fire-and-forget ds_writes, chunked at LIST_CAP), then all 64 lanes
//     process the list lane-strided with 1-deep prefetch. Removes the
//     max(num)-divergent serial per-lane loop; gathers become cell-contiguous.
//     Exactness: identical candidate set/keys; the per-lane top16-with-drop-max
//     union argument is independent of which lane processes which candidate.
// (b) rank-count selection: neighbor order is irrelevant downstream (max over K,
//     means), only the exact SET matters. The stop check proves >=16 buffered
//     keys < tkey, so all true top-16 are < tkey; compact those keys into LDS,
//     rank each against the compacted list via broadcast reads; rank<16 wins,
//     rank = exact global rank (every key smaller than a winner is provably
//     buffered and < tkey). Replaces 16 rounds of 64-bit wave-argmin + serial
//     single-lane rescans. Brute/overflow (c>CSEL_CAP) keep old extraction.
__global__ __launch_bounds__(256, 4) void knn_kernel(const float4* __restrict__ spos,
                                                     const int* __restrict__ cnt,
                                                     const int* __restrict__ offs,
                                                     int* __restrict__ knn,
                                                     float* __restrict__ spatial) {
    __shared__ unsigned long long buf[4][16][64];
    __shared__ int lst[4][LIST_CAP];
    int lane = threadIdx.x & 63;
    int wv   = threadIdx.x >> 6;
    int s    = blockIdx.x * 4 + wv;       // query slot in sorted order
    float4 q = spos[s];
    float qx = q.x, qy = q.y, qz = q.z;
    float qxx = sumsq3(qx, qy, qz);
    int b  = s >> 13;
    int nq = __float_as_int(q.w);
    int cx = min(GD - 1, max(0, (int)floorf((qx - ORGN) * INVH)));
    int cy = min(GD - 1, max(0, (int)floorf((qy - ORGN) * INVH)));
    int cz = min(GD - 1, max(0, (int)floorf((qz - ORGN) * INVH)));
    const int* cb = cnt  + b * NCELL;
    const int* ob = offs + b * NCELL;     // offs is a GLOBAL scan; base below is a global slot

    unsigned long long* mybuf = &buf[wv][0][lane];   // element j at mybuf[j*64]
    unsigned long long minkey = ~0ULL;
    unsigned long long maxkey = 0;
    int nbuf = 0;
    unsigned long long tkey = 0;

    int R = 0;
    int brute = 0;
    while (true) {
        int S = (R == 0) ? 1 : 24 * R * R + 2;
        for (int u0 = 0; u0 < S; u0 += 64) {
            int u = u0 + lane;
            int num = 0, base = 0;
            if (u < S) {
                int dx = 0, dy = 0, dz = 0;
                if (R > 0) shell_decode(R, u, dx, dy, dz);
                int xc = cx + dx, yc = cy + dy, zc = cz + dz;
                if ((unsigned)xc < GD && (unsigned)yc < GD && (unsigned)zc < GD) {
                    int cell = (zc * GD + yc) * GD + xc;
                    num  = cb[cell];
                    base = ob[cell];
                }
            }
            // balanced expand + process (chunked at LIST_CAP)
            int rem = num, cur = base;
            while (true) {
                int inc = wave_scan_incl(rem, lane);
                int tot = __shfl(inc, 63, 64);
                if (tot == 0) break;
                int excl = inc - rem;
                int space = LIST_CAP - excl;
                int take = min(rem, max(space, 0));
                for (int j = 0; j < take; ++j) lst[wv][excl + j] = cur + j;
                rem -= take; cur += take;
                int n = min(tot, LIST_CAP);
                asm volatile("s_waitcnt lgkmcnt(0)" ::: "memory");
                __builtin_amdgcn_sched_barrier(0);
                int t = lane;
                int sp_cur = (t < n) ? lst[wv][t] : 0;
                float4 p_cur = spos[sp_cur];
                for (; t < n; t += 64) {
                    int tn = t + 64;
                    int sp_nx = (tn < n) ? lst[wv][tn] : 0;
                    float4 p_nx = spos[sp_nx];               // prefetch next
                    float d = pdist4(qx, qy, qz, qxx, p_cur.x, p_cur.y, p_cur.z);
                    int oi = __float_as_int(p_cur.w);
                    unsigned long long key = ((unsigned long long)fkey(d) << 27)
                                           | ((unsigned long long)(unsigned)oi << 14)
                                           | (unsigned)sp_cur;
                    if (nbuf < 16) {
                        mybuf[(size_t)nbuf * 64] = key;
                        ++nbuf;
                        minkey = (key < minkey) ? key : minkey;
                        maxkey = (key > maxkey) ? key : maxkey;
                    } else if (key < maxkey) {
                        unsigned long long vmax = 0, v2 = 0;
                        int pmax = 0;
                        #pragma unroll
                        for (int j = 0; j < 16; ++j) {
                            unsigned long long v = mybuf[(size_t)j * 64];
                            if (v > vmax) { v2 = vmax; vmax = v; pmax = j; }
                            else if (v > v2) { v2 = v; }
                        }
                        mybuf[(size_t)pmax * 64] = key;
                        maxkey = (key > v2) ? key : v2;
                        minkey = (key < minkey) ? key : minkey;
                    }
                    sp_cur = sp_nx; p_cur = p_nx;
                }
                asm volatile("s_waitcnt lgkmcnt(0)" ::: "memory");
                __builtin_amdgcn_sched_barrier(0);
            }
        }
        // stop: >=16 candidates strictly inside the exact box-face margin (R5-proven).
        float mlx = qx - (ORGN + (float)(cx - R) * HCELL);
        float mhx = (ORGN + (float)(cx + R + 1) * HCELL) - qx;
        float mly = qy - (ORGN + (float)(cy - R) * HCELL);
        float mhy = (ORGN + (float)(cy + R + 1) * HCELL) - qy;
        float mlz = qz - (ORGN + (float)(cz - R) * HCELL);
        float mhz = (ORGN + (float)(cz + R + 1) * HCELL) - qz;
        float margin = fminf(fminf(fminf(mlx, mhx), fminf(mly, mhy)), fminf(mlz, mhz));
        float thr = margin * margin - 1e-4f;   // shave covers fp cancellation in pdist4
        tkey = ((unsigned long long)(fkey(thr) + 1u)) << 27;
        int c = 0;
        for (int j = 0; j < nbuf; ++j) c += (mybuf[(size_t)j * 64] < tkey) ? 1 : 0;
        for (int o = 32; o > 0; o >>= 1) c += __shfl_xor(c, o, 64);
        if (c >= 16) break;
        if (R >= RMAX_GRID) { brute = 1; break; }
        ++R;
    }

    if (brute) {
        // exact fallback: rescan ALL points of this batch, coalesced.
        // Reset buffer so every point is seen exactly once (no duplicates).
        nbuf = 0; minkey = ~0ULL; maxkey = 0;
        int sbase = b << 13;
        for (int i = lane; i < NPTS; i += 64) {
            float4 p = spos[sbase + i];
            float d = pdist4(qx, qy, qz, qxx, p.x, p.y, p.z);
            int oi = __float_as_int(p.w);
            unsigned long long key = ((unsigned long long)fkey(d) << 27)
                                   | ((unsigned long long)(unsigned)oi << 14)
                                   | (unsigned)(sbase + i);
            if (nbuf < 16) {
                mybuf[(size_t)nbuf * 64] = key;
                ++nbuf;
                minkey = (key < minkey) ? key : minkey;
                maxkey = (key > maxkey) ? key : maxkey;
            } else if (key < maxkey) {
                unsigned long long vmax = 0, v2 = 0;
                int pmax = 0;
                #pragma unroll
                for (int j = 0; j < 16; ++j) {
                    unsigned long long v = mybuf[(size_t)j * 64];
                    if (v > vmax) { v2 = vmax; vmax = v; pmax = j; }
                    else if (v > v2) { v2 = v; }
                }
                mybuf[(size_t)pmax * 64] = key;
                maxkey = (key > v2) ? key : v2;
                minkey = (key < minkey) ? key : minkey;
            }
        }
    } else {
        // rank-count selection fast path (order-free exact top-16 set)
        int ki = 0;
        for (int j = 0; j < nbuf; ++j) ki += (mybuf[(size_t)j * 64] < tkey) ? 1 : 0;
        int incl = wave_scan_incl(ki, lane);
        int csel = __shfl(incl, 63, 64);
        if (csel <= CSEL_CAP) {
            unsigned long long* sel = (unsigned long long*)&lst[wv][0];
            int w = incl - ki;
            for (int j = 0; j < nbuf; ++j) {
                unsigned long long v = mybuf[(size_t)j * 64];
                if (v < tkey) sel[w++] = v;
            }
            asm volatile("s_waitcnt lgkmcnt(0)" ::: "memory");
            __builtin_amdgcn_sched_barrier(0);
            float rx = 0.f, ry = 0.f, rz = 0.f, rd = 0.f;
            for (int t = lane; t < csel; t += 64) {
                unsigned long long kt = sel[t];
                int r = 0;
                #pragma unroll 4
                for (int j = 0; j < csel; ++j) r += (sel[j] < kt) ? 1 : 0;   // broadcast reads
                if (r < 16) {
                    int sp = (int)(kt & 0x3FFFu);
                    int oi = (int)((kt >> 14) & 0x1FFFu);
                    float4 p = spos[sp];
                    float dx = p.x - qx, dy = p.y - qy, dz = p.z - qz;
                    float dl = sqrtf(__fadd_rn(__fadd_rn(__fmul_rn(dx, dx), __fmul_rn(dy, dy)), __fmul_rn(dz, dz)));
                    knn[(((size_t)b << 13) + nq) * 16 + r] = oi;
                    rx += dx; ry += dy; rz += dz; rd += dl;
                }
            }
            for (int o = 32; o > 0; o >>= 1) {
                rx += __shfl_xor(rx, o, 64);
                ry += __shfl_xor(ry, o, 64);
                rz += __shfl_xor(rz, o, 64);
                rd += __shfl_xor(rd, o, 64);
            }
            if (lane == 0) {
                const float inv16 = 0.0625f;
                spatial[((size_t)b * 4 + 0) * NPTS + nq] = rx * inv16;
                spatial[((size_t)b * 4 + 1) * NPTS + nq] = ry * inv16;
                spatial[((size_t)b * 4 + 2) * NPTS + nq] = rz * inv16;
                spatial[((size_t)b * 4 + 3) * NPTS + nq] = rd * inv16;
            }
            return;
        }
    }

    // fallback: exact global top-16 via 16 rounds of wave-wide u64 argmin
    unsigned long long keep = ~0ULL;
    for (int k = 0; k < 16; ++k) {
        unsigned long long m = minkey;
        for (int o = 32; o > 0; o >>= 1) {
            unsigned long long pv = shflx64(m, o);
            m = (pv < m) ? pv : m;
        }
        unsigned long long bal = __ballot(minkey == m);
        int wl = __ffsll((long long)bal) - 1;
        if (lane == wl) {
            int pos = 0;
            for (int j = 0; j < nbuf; ++j) if (mybuf[(size_t)j * 64] == m) pos = j;
            --nbuf;
            mybuf[(size_t)pos * 64] = mybuf[(size_t)nbuf * 64];
            unsigned long long nm = ~0ULL;
            for (int j = 0; j < nbuf; ++j) {
                unsigned long long v = mybuf[(size_t)j * 64];
                nm = (v < nm) ? v : nm;
            }
            minkey = nm;
        }
        if (lane == k) keep = m;
    }

    float rx = 0.f, ry = 0.f, rz = 0.f, rd = 0.f;
    if (lane < 16) {
        int sp = (int)(keep & 0x3FFFu);
        int oi = (int)((keep >> 14) & 0x1FFFu);
        float4 p = spos[sp];
        rx = p.x - qx; ry = p.y - qy; rz = p.z - qz;
        rd = sqrtf(__fadd_rn(__fadd_rn(__fmul_rn(rx, rx), __fmul_rn(ry, ry)), __fmul_rn(rz, rz)));
        knn[(((size_t)b << 13) + nq) * 16 + lane] = oi;
    }
    for (int o = 8; o > 0; o >>= 1) {
        rx += __shfl_xor(rx, o, 64);
        ry += __shfl_xor(ry, o, 64);
        rz += __shfl_xor(rz, o, 64);
        rd += __shfl_xor(rd, o, 64);
    }
    if (lane == 0) {
        const float inv16 = 0.0625f;
        spatial[((size_t)b * 4 + 0) * NPTS + nq] = rx * inv16;
        spatial[((size_t)b * 4 + 1) * NPTS + nq] = ry * inv16;
        spatial[((size_t)b * 4 + 2) * NPTS + nq] = rz * inv16;
        spatial[((size_t)b * 4 + 3) * NPTS + nq] = rd * inv16;
    }
}

// ---------------- x[B,C,N] -> xT[B,N,C] ----------------
__global__ void transpose_k(const float* __restrict__ x, float* __restrict__ xT) {
    __shared__ float tl[32][33];
    int b = blockIdx.z;
    int n0 = blockIdx.x * 32, c0 = blockIdx.y * 32;
    int tx = threadIdx.x, ty = threadIdx.y;
    const float* xb = x + (size_t)b * 128 * NN;
    float* xtb = xT + (size_t)b * NN * 128;
    for (int i = 0; i < 32; i += 8) tl[ty + i][tx] = xb[(size_t)(c0 + ty + i) * NN + n0 + tx];
    __syncthreads();
    for (int i = 0; i < 32; i += 8) xtb[(size_t)(n0 + ty + i) * 128 + c0 + tx] = tl[tx][ty + i];
}

// ---------------- max_k(x[:,idx_k]) - x  -> md[B,128,N] ----------------
__global__ __launch_bounds__(256) void md_k(const float* __restrict__ xT,
                                            const int* __restrict__ knn,
                                            float* __restrict__ md) {
    __shared__ int ki[8][16];
    __shared__ float smd[8][132];
    int b = blockIdx.y;
    int n0 = blockIdx.x * 8;
    int tid = threadIdx.x;
    if (tid < 128) ki[tid >> 4][tid & 15] = knn[(((size_t)b << 13) + n0 + (tid >> 4)) * 16 + (tid & 15)];
    __syncthreads();
    int nl = tid >> 5;
    int c4 = (tid & 31) * 4;
    const float* xb = xT + (size_t)b * NPTS * 128;
    float4 m = make_float4(-3.0e38f, -3.0e38f, -3.0e38f, -3.0e38f);
    #pragma unroll
    for (int k = 0; k < 16; ++k) {
        const float4 g = *(const float4*)(xb + (size_t)ki[nl][k] * 128 + c4);
        m.x = fmaxf(m.x, g.x); m.y = fmaxf(m.y, g.y); m.z = fmaxf(m.z, g.z); m.w = fmaxf(m.w, g.w);
    }
    const float4 own = *(const float4*)(xb + (size_t)(n0 + nl) * 128 + c4);
    m.x -= own.x; m.y -= own.y; m.z -= own.z; m.w -= own.w;
    *(float4*)(&smd[nl][c4]) = m;
    __syncthreads();
    for (int r = 0; r < 4; ++r) {
        int c = (tid >> 3) + 32 * r;
        int n2 = tid & 7;
        md[((size_t)b * 128 + c) * NN + n0 + n2] = smd[n2][c];
    }
}

// ---------------- fold conv-bias + BN into per-channel scale/shift ----------------
__global__ void prep_k(const float* bb1, const float* g1, const float* be1, const float* m1, const float* v1,
                       const float* bb2, const float* g2, const float* be2, const float* m2, const float* v2,
                       const float* sb1, const float* gs,  const float* bes, const float* ms, const float* vs,
                       const float* sb2,
                       const float* ab1, const float* ga,  const float* bea, const float* ma, const float* va,
                       const float* ab2, float* sc) {
    int t = threadIdx.x;
    if (t < 128) {
        float i1 = g1[t] / sqrtf(v1[t] + 1e-5f);
        sc[t] = i1;        sc[128 + t] = bb1[t] * i1 + be1[t] - m1[t] * i1;
        float i2 = g2[t] / sqrtf(v2[t] + 1e-5f);
        sc[256 + t] = i2;  sc[384 + t] = bb2[t] * i2 + be2[t] - m2[t] * i2;
        sc[832 + t] = 1.0f; sc[960 + t] = ab2[t];
    }
    if (t < 32) {
        float is = gs[t] / sqrtf(vs[t] + 1e-5f);
        sc[512 + t] = is;  sc[544 + t] = sb1[t] * is + bes[t] - ms[t] * is;
    }
    if (t < 64) {
        sc[576 + t] = 1.0f; sc[640 + t] = sb2[t];
        float ia = ga[t] / sqrtf(va[t] + 1e-5f);
        sc[704 + t] = ia;  sc[768 + t] = ab1[t] * ia + bea[t] - ma[t] * ia;
    }
}

// ---------------- generic 1x1-conv (+folded BN, activation) ----------------
// ACT: 0=none, 1=relu, 2=sigmoid + fused "dout = x + y2*attn"
template <int O, int K, int TILE_N, int SPLIT, int ACT>
__global__ __launch_bounds__(256) void conv_bn(const float* __restrict__ srcA,
                                               const float* __restrict__ srcB,
                                               const float* __restrict__ W,
                                               const float* __restrict__ scale,
                                               const float* __restrict__ shift,
                                               float* __restrict__ out,
                                               const float* __restrict__ resx,
                                               const float* __restrict__ y2,
                                               float* __restrict__ dout) {
    constexpr int KC  = (K < 64) ? K : 64;
    constexpr int NT4 = TILE_N / 4;
    constexpr int O4  = O / 4;
    static_assert(NT4 * O4 == 256, "thread mapping");
    __shared__ float wT[KC][O + 4];
    __shared__ float inT[KC][TILE_N];
    int tid = threadIdx.x;
    int b = blockIdx.z;
    int n0 = blockIdx.x * TILE_N;
    int n_thr = tid % NT4;          // n fastest -> coalesced stores
    int o_thr = tid / NT4;
    float acc[4][4] = {{0.f, 0.f, 0.f, 0.f}, {0.f, 0.f, 0.f, 0.f}, {0.f, 0.f, 0.f, 0.f}, {0.f, 0.f, 0.f, 0.f}};

    for (int k0 = 0; k0 < K; k0 += KC) {
        for (int idx = tid; idx < KC * O; idx += 256) {
            int cc = idx % KC;
            int o  = idx / KC;
            wT[cc][o] = W[(size_t)o * K + k0 + cc];
        }
        for (int idx = tid; idx < KC * NT4; idx += 256) {
            int cc = idx / NT4;
            int nf = idx % NT4;
            int cg = k0 + cc;
            const float* src = (cg < SPLIT)
                ? (srcA + ((size_t)b * SPLIT + cg) * NN)
                : (srcB + ((size_t)b * (K - SPLIT) + (cg - SPLIT)) * NN);
            *(float4*)(&inT[cc][nf * 4]) = *(const float4*)(src + n0 + nf * 4);
        }
        __syncthreads();
        #pragma unroll 8
        for (int c = 0; c < KC; ++c) {
            float4 wv = *(const float4*)(&wT[c][o_thr * 4]);
            float4 iv = *(const float4*)(&inT[c][n_thr * 4]);
            acc[0][0] = fmaf(wv.x, iv.x, acc[0][0]); acc[0][1] = fmaf(wv.x, iv.y, acc[0][1]);
            acc[0][2] = fmaf(wv.x, iv.z, acc[0][2]); acc[0][3] = fmaf(wv.x, iv.w, acc[0][3]);
            acc[1][0] = fmaf(wv.y, iv.x, acc[1][0]); acc[1][1] = fmaf(wv.y, iv.y, acc[1][1]);
            acc[1][2] = fmaf(wv.y, iv.z, acc[1][2]); acc[1][3] = fmaf(wv.y, iv.w, acc[1][3]);
            acc[2][0] = fmaf(wv.z, iv.x, acc[2][0]); acc[2][1] = fmaf(wv.z, iv.y, acc[2][1]);
            acc[2][2] = fmaf(wv.z, iv.z, acc[2][2]); acc[2][3] = fmaf(wv.z, iv.w, acc[2][3]);
            acc[3][0] = fmaf(wv.w, iv.x, acc[3][0]); acc[3][1] = fmaf(wv.w, iv.y, acc[3][1]);
            acc[3][2] = fmaf(wv.w, iv.z, acc[3][2]); acc[3][3] = fmaf(wv.w, iv.w, acc[3][3]);
        }
        __syncthreads();
    }
    #pragma unroll
    for (int j = 0; j < 4; ++j) {
        int o = o_thr * 4 + j;
        float scv = scale[o], shv = shift[o];
        float4 v;
        v.x = fmaf(acc[j][0], scv, shv);
        v.y = fmaf(acc[j][1], scv, shv);
        v.z = fmaf(acc[j][2], scv, shv);
        v.w = fmaf(acc[j][3], scv, shv);
        size_t obase = ((size_t)b * O + o) * NN + n0 + n_thr * 4;
        if (ACT == 1) {
            v.x = fmaxf(v.x, 0.f); v.y = fmaxf(v.y, 0.f); v.z = fmaxf(v.z, 0.f); v.w = fmaxf(v.w, 0.f);
            *(float4*)(out + obase) = v;
        } else if (ACT == 2) {
            float4 xr = *(const float4*)(resx + obase);
            float4 yr = *(const float4*)(y2 + obase);
            v.x = xr.x + yr.x / (1.f + __expf(-v.x));
            v.y = xr.y + yr.y / (1.f + __expf(-v.y));
            v.z = xr.z + yr.z / (1.f + __expf(-v.z));
            v.w = xr.w + yr.w / (1.f + __expf(-v.w));
            *(float4*)(dout + obase) = v;
        } else {
            *(float4*)(out + obase) = v;
        }
    }
}

extern "C" void kernel_launch(void* const* d_in, const int* in_sizes, int n_in,
                              void* d_out, int out_size, void* d_ws, size_t ws_size,
                              hipStream_t stream) {
    (void)in_sizes; (void)n_in; (void)out_size; (void)ws_size;
    const float* x    = (const float*)d_in[0];
    const float* xyz  = (const float*)d_in[1];
    const float* bw1  = (const float*)d_in[2];
    const float* bb1  = (const float*)d_in[3];
    const float* bn1g = (const float*)d_in[4];
    const float* bn1b = (const float*)d_in[5];
    const float* bn1m = (const float*)d_in[6];
    const float* bn1v = (const float*)d_in[7];
    const float* bw2  = (const float*)d_in[8];
    const float* bb2  = (const float*)d_in[9];
    const float* bn2g = (const float*)d_in[10];
    const float* bn2b = (const float*)d_in[11];
    const float* bn2m = (const float*)d_in[12];
    const float* bn2v = (const float*)d_in[13];
    const float* sw1  = (const float*)d_in[14];
    const float* sb1  = (const float*)d_in[15];
    const float* sbng = (const float*)d_in[16];
    const float* sbnb = (const float*)d_in[17];
    const float* sbnm = (const float*)d_in[18];
    const float* sbnv = (const float*)d_in[19];
    const float* sw2  = (const float*)d_in[20];
    const float* sb2  = (const float*)d_in[21];
    const float* aw1  = (const float*)d_in[22];
    const float* ab1  = (const float*)d_in[23];
    const float* abng = (const float*)d_in[24];
    const float* abnb = (const float*)d_in[25];
    const float* abnm = (const float*)d_in[26];
    const float* abnv = (const float*)d_in[27];
    const float* aw2  = (const float*)d_in[28];
    const float* ab2  = (const float*)d_in[29];

    char* ws = (char*)d_ws;
    int*    cnt    = (int*)(ws + OFF_CNT);
    int*    offs   = (int*)(ws + OFF_OFFS);
    int*    cellid = (int*)(ws + OFF_CELLID);
    int*    rank   = (int*)(ws + OFF_RANK);
    float4* spos   = (float4*)(ws + OFF_SPOS);
    int*    knn    = (int*)(ws + OFF_KNN);
    float*  spat   = (float*)(ws + OFF_SPATIAL);
    float*  xT     = (float*)(ws + OFF_XT);
    float*  md     = (float*)(ws + OFF_MD);
    float*  s1b    = (float*)(ws + OFF_S1);
    float*  sfb    = (float*)(ws + OFF_SF);
    float*  y1b    = (float*)(ws + OFF_Y1);
    float*  y2b    = (float*)(ws + OFF_Y2);
    float*  a1b    = (float*)(ws + OFF_A1);
    float*  sc     = (float*)(ws + OFF_SC);
    int*    bsum   = (int*)(ws + OFF_BSUM);
    int*    bpre   = (int*)(ws + OFF_BPRE);
    float*  dout   = (float*)d_out;

    hipMemsetAsync(cnt, 0, (size_t)TOTC * 4, stream);
    cell_build<<<dim3((NTOT + 255) / 256), 256, 0, stream>>>(xyz, cnt, cellid, rank);
    scan_sums<<<dim3(NBLK_SCAN), 256, 0, stream>>>(cnt, bsum);
    scan_top<<<dim3(1), 512, 0, stream>>>(bsum, bpre);
    scan_write<<<dim3(NBLK_SCAN), 256, 0, stream>>>(cnt, bpre, offs);
    scatter_k<<<dim3((NTOT + 255) / 256), 256, 0, stream>>>(xyz, cellid, rank, offs, spos);
    knn_kernel<<<dim3(NTOT / 4), 256, 0, stream>>>(spos, cnt, offs, knn, spat);
    transpose_k<<<dim3(NPTS / 32, 128 / 32, NB), dim3(32, 8), 0, stream>>>(x, xT);
    md_k<<<dim3(NPTS / 8, NB), 256, 0, stream>>>(xT, knn, md);
    prep_k<<<1, 128, 0, stream>>>(bb1, bn1g, bn1b, bn1m, bn1v,
                                  bb2, bn2g, bn2b, bn2m, bn2v,
                                  sb1, sbng, sbnb, sbnm, sbnv,
                                  sb2,
                                  ab1, abng, abnb, abnm, abnv,
                                  ab2, sc);
    // spatial MLP: 4->32 (bn,relu), 32->64
    conv_bn<32, 4, 128, 4, 1><<<dim3(NPTS / 128, 1, NB), 256, 0, stream>>>(
        spat, spat, sw1, sc + 512, sc + 544, s1b, nullptr, nullptr, nullptr);
    conv_bn<64, 32, 64, 32, 0><<<dim3(NPTS / 64, 1, NB), 256, 0, stream>>>(
        s1b, s1b, sw2, sc + 576, sc + 640, sfb, nullptr, nullptr, nullptr);
    // boundary net: [x;md] 256->128 (bn,relu), 128->128 (bn,relu)
    conv_bn<128, 256, 32, 128, 1><<<dim3(NPTS / 32, 1, NB), 256, 0, stream>>>(
        x, md, bw1, sc + 0, sc + 128, y1b, nullptr, nullptr, nullptr);
    conv_bn<128, 128, 32, 128, 1><<<dim3(NPTS / 32, 1, NB), 256, 0, stream>>>(
        y1b, y1b, bw2, sc + 256, sc + 384, y2b, nullptr, nullptr, nullptr);
    // attention: [x;sfeat] 192->64 (bn,relu), 64->128 sigmoid + final fuse
    conv_bn<64, 192, 64, 128, 1><<<dim3(NPTS / 64, 1, NB), 256, 0, stream>>>(
        x, sfb, aw1, sc + 704, sc + 768, a1b, nullptr, nullptr, nullptr);
    conv_bn<128, 64, 32, 64, 2><<<dim3(NPTS / 32, 1, NB), 256, 0, stream>>>(
        a1b, a1b, aw2, sc + 832, sc + 960, dout, x, y2b, dout);
}

// Round 3
// 395.688 us; speedup vs baseline: 1.1438x; 1.0798x over previous
//
#include <hip/hip_runtime.h>
#include <math.h>

#define NPTS  8192
#define NB    2
#define NTOT  (NPTS*NB)
#define GD    60
#define NCELL (GD*GD*GD)
#define TOTC  (NB*NCELL)
#define HCELL 0.2f
#define INVH  5.0f
#define ORGN  (-6.0f)
#define NN    8192
#define SCAN_CHUNK 1024
#define NBLK_SCAN  ((TOTC + SCAN_CHUNK - 1) / SCAN_CHUNK)
#define RMAX_GRID 4   // beyond this shell radius, fall back to exact brute-force scan
#define RSTART    2   // scan the full (2*RSTART+1)^3 box before the first stop-check
#define LIST_CAP 512  // per-wave expansion list (ints); reused as sel keys (256 u64)
#define CSEL_CAP 192  // rank-select path cap; larger falls back to 16-round extraction

// ---------------- workspace layout (bytes) ----------------
#define OFF_CNT     ((size_t)0)
#define OFF_OFFS    (OFF_CNT    + (size_t)TOTC*4)
#define OFF_CELLID  (OFF_OFFS   + (size_t)TOTC*4)
#define OFF_RANK    (OFF_CELLID + (size_t)NTOT*4)
#define OFF_SPOS    (OFF_RANK   + (size_t)NTOT*4)          // float4 * NTOT (w = origidx bits)
#define OFF_KNN     (OFF_SPOS   + (size_t)NTOT*16)         // int * NTOT*16
#define OFF_SPATIAL (OFF_KNN    + (size_t)NTOT*16*4)       // [B,4,N]
#define OFF_XT      (OFF_SPATIAL+ (size_t)NB*4*NPTS*4)     // [B,N,128]
#define OFF_MD      (OFF_XT     + (size_t)NB*128*NPTS*4)   // [B,128,N]
#define OFF_S1      (OFF_MD     + (size_t)NB*128*NPTS*4)   // [B,32,N]
#define OFF_SF      (OFF_S1     + (size_t)NB*32*NPTS*4)    // [B,64,N]
#define OFF_Y1      (OFF_SF     + (size_t)NB*64*NPTS*4)    // [B,128,N]
#define OFF_Y2      (OFF_Y1     + (size_t)NB*128*NPTS*4)   // [B,128,N]
#define OFF_A1      (OFF_Y2     + (size_t)NB*128*NPTS*4)   // [B,64,N]
#define OFF_SC      (OFF_A1     + (size_t)NB*64*NPTS*4)    // 1088 floats
#define OFF_BSUM    (OFF_SC     + (size_t)1088*4)          // NBLK_SCAN ints
#define OFF_BPRE    (OFF_BSUM   + (size_t)NBLK_SCAN*4)     // NBLK_SCAN ints

// Replicate reference arithmetic exactly (no fma contraction).
static __device__ __forceinline__ float sumsq3(float x, float y, float z) {
    return __fadd_rn(__fadd_rn(__fmul_rn(x, x), __fmul_rn(y, y)), __fmul_rn(z, z));
}
static __device__ __forceinline__ float pdist4(float qx, float qy, float qz, float qxx,
                                               float px, float py, float pz) {
    float pxx = sumsq3(px, py, pz);
    float dot = __fadd_rn(__fadd_rn(__fmul_rn(qx, px), __fmul_rn(qy, py)), __fmul_rn(qz, pz));
    return __fsub_rn(__fadd_rn(qxx, pxx), __fadd_rn(dot, dot));
}
// monotone unsigned key for float (handles tiny negative self-distance)
static __device__ __forceinline__ unsigned fkey(float f) {
    unsigned b = __float_as_uint(f);
    return b ^ ((unsigned)(((int)b) >> 31) | 0x80000000u);
}
static __device__ __forceinline__ unsigned long long shflx64(unsigned long long v, int m) {
    unsigned lo = __shfl_xor((unsigned)v, m, 64);
    unsigned hi = __shfl_xor((unsigned)(v >> 32), m, 64);
    return ((unsigned long long)hi << 32) | lo;
}
// inclusive wave prefix-sum (all 64 lanes active)
static __device__ __forceinline__ int wave_scan_incl(int v, int lane) {
    #pragma unroll
    for (int d = 1; d < 64; d <<= 1) {
        int u = __shfl_up(v, d, 64);
        v += (lane >= d) ? u : 0;
    }
    return v;
}

// ---------------- grid build ----------------
__global__ void cell_build(const float* __restrict__ xyz, int* __restrict__ cnt,
                           int* __restrict__ cellid, int* __restrict__ rank) {
    int t = blockIdx.x * 256 + threadIdx.x;
    if (t >= NTOT) return;
    const float* p = xyz + (size_t)t * 3;
    float x = p[0], y = p[1], z = p[2];
    int cx = min(GD - 1, max(0, (int)floorf((x - ORGN) * INVH)));
    int cy = min(GD - 1, max(0, (int)floorf((y - ORGN) * INVH)));
    int cz = min(GD - 1, max(0, (int)floorf((z - ORGN) * INVH)));
    int gcell = (t >> 13) * NCELL + (cz * GD + cy) * GD + cx;
    rank[t] = atomicAdd(&cnt[gcell], 1);
    cellid[t] = gcell;
}

// -------- hierarchical exclusive scan of cnt[TOTC] -> offs[TOTC] --------
__global__ __launch_bounds__(256) void scan_sums(const int* __restrict__ cnt, int* __restrict__ bsum) {
    __shared__ int red[256];
    int blk = blockIdx.x, t = threadIdx.x;
    int i0 = blk * SCAN_CHUNK + t * 4;
    int s = 0;
    if (i0 + 3 < TOTC) {
        int4 v = *(const int4*)(cnt + i0);
        s = v.x + v.y + v.z + v.w;
    } else {
        for (int j = 0; j < 4; ++j) if (i0 + j < TOTC) s += cnt[i0 + j];
    }
    red[t] = s;
    __syncthreads();
    for (int d = 128; d > 0; d >>= 1) {
        if (t < d) red[t] += red[t + d];
        __syncthreads();
    }
    if (t == 0) bsum[blk] = red[0];
}

__global__ __launch_bounds__(512) void scan_top(const int* __restrict__ bsum, int* __restrict__ bpre) {
    __shared__ int ps[512];
    int t = threadIdx.x;
    int v = (t < NBLK_SCAN) ? bsum[t] : 0;
    ps[t] = v;
    __syncthreads();
    for (int d = 1; d < 512; d <<= 1) {
        int u = 0;
        if (t >= d) u = ps[t - d];
        __syncthreads();
        ps[t] += u;
        __syncthreads();
    }
    if (t < NBLK_SCAN) bpre[t] = ps[t] - v;   // exclusive
}

__global__ __launch_bounds__(256) void scan_write(const int* __restrict__ cnt, const int* __restrict__ bpre,
                                                  int* __restrict__ offs) {
    __shared__ int ps[256];
    int blk = blockIdx.x, t = threadIdx.x;
    int i0 = blk * SCAN_CHUNK + t * 4;
    int a = 0, b = 0, c = 0, d = 0;
    if (i0 + 3 < TOTC) {
        int4 v = *(const int4*)(cnt + i0);
        a = v.x; b = v.y; c = v.z; d = v.w;
    } else {
        if (i0 + 0 < TOTC) a = cnt[i0 + 0];
        if (i0 + 1 < TOTC) b = cnt[i0 + 1];
        if (i0 + 2 < TOTC) c = cnt[i0 + 2];
        if (i0 + 3 < TOTC) d = cnt[i0 + 3];
    }
    int s = a + b + c + d;
    ps[t] = s;
    __syncthreads();
    for (int dd = 1; dd < 256; dd <<= 1) {
        int u = 0;
        if (t >= dd) u = ps[t - dd];
        __syncthreads();
        ps[t] += u;
        __syncthreads();
    }
    int base = bpre[blk] + ps[t] - s;
    if (i0 + 0 < TOTC) offs[i0 + 0] = base;
    if (i0 + 1 < TOTC) offs[i0 + 1] = base + a;
    if (i0 + 2 < TOTC) offs[i0 + 2] = base + a + b;
    if (i0 + 3 < TOTC) offs[i0 + 3] = base + a + b + c;
}

__global__ void scatter_k(const float* __restrict__ xyz, const int* __restrict__ cellid,
                          const int* __restrict__ rank, const int* __restrict__ offs,
                          float4* __restrict__ spos) {
    int t = blockIdx.x * 256 + threadIdx.x;
    if (t >= NTOT) return;
    const float* p = xyz + (size_t)t * 3;
    float x = p[0], y = p[1], z = p[2];
    int pos = offs[cellid[t]] + rank[t];
    spos[pos] = make_float4(x, y, z, __int_as_float(t & (NPTS - 1)));
}

// decode u-th cell of Chebyshev shell R (R>=1); S(R)=24R^2+2
static __device__ __forceinline__ void shell_decode(int R, int u, int& dx, int& dy, int& dz) {
    int L = 2 * R + 1, P = L * L;
    if (u < 2 * P) {
        int v = (u < P) ? u : u - P;
        dz = (u < P) ? -R : R;
        dx = v % L - R;
        dy = v / L - R;
    } else {
        int w = u - 2 * P;
        int ring = w / (8 * R);
        int p = w - ring * 8 * R;
        dz = ring - (R - 1);
        if (p < 2 * R)      { dx = p - R;            dy = -R; }
        else if (p < 4 * R) { dx = R;                dy = p - 3 * R; }
        else if (p < 6 * R) { dx = 5 * R - p;        dy = R; }
        else                { dx = -R;               dy = 7 * R - p; }
    }
}

// ---------------- exact KNN: one wave per BLOCK per query ----------------
// R9 changes (candidate keys/stop math/brute = R8 verbatim):
// (a) 64-thread blocks (block == wave). R8's 4-wave blocks held 40KB LDS until
//     the SLOWEST wave finished -> measured occupancy 12.6% = 4.03 waves/CU =
//     one live wave per resident block; all gather latency exposed. Now each
//     finished wave retires and frees its 10,240B LDS immediately ->
//     16 blocks/CU resident (160KB/10KB), 4x latency hiding.
// (b) start with the full 5^3 box (R<=2): counts/offsets for both 64-cell
//     halves are issued in one flight, one stop-check instead of three.
//     Core queries almost always need R=2 anyway; superset of candidates is
//     exact (selection is threshold-certified).
// (c) tight selection threshold: margins obey margin(R') = margin0 + R'*h;
//     count buffered keys against margins {R-2,R-1,R} in one pass and select
//     with the SMALLEST margin having >=16 keys (typ. 30-60 keys instead of
//     ~300) -> rank-count loop stays O(csel^2/64) small. Exactness: any
//     threshold t with "all points with key<t scanned" works; true top-16 are
//     the 16 globally smallest of >=16 keys < t, dropped keys can't perturb
//     ranks below 16 (a dropped key has 16 lane-local better keys, all < it).
__global__ __launch_bounds__(64, 4) void knn_kernel(const float4* __restrict__ spos,
                                                    const int* __restrict__ cnt,
                                                    const int* __restrict__ offs,
                                                    int* __restrict__ knn,
                                                    float* __restrict__ spatial) {
    __shared__ unsigned long long buf[16][64];
    __shared__ int lst[LIST_CAP];
    int lane = threadIdx.x;
    int s    = blockIdx.x;                // query slot in sorted order
    float4 q = spos[s];
    float qx = q.x, qy = q.y, qz = q.z;
    float qxx = sumsq3(qx, qy, qz);
    int b  = s >> 13;
    int nq = __float_as_int(q.w);
    int cx = min(GD - 1, max(0, (int)floorf((qx - ORGN) * INVH)));
    int cy = min(GD - 1, max(0, (int)floorf((qy - ORGN) * INVH)));
    int cz = min(GD - 1, max(0, (int)floorf((qz - ORGN) * INVH)));
    const int* cb = cnt  + b * NCELL;
    const int* ob = offs + b * NCELL;     // offs is a GLOBAL scan; base below is a global slot

    unsigned long long* mybuf = &buf[0][lane];   // element j at mybuf[j*64]
    unsigned long long minkey = ~0ULL;
    unsigned long long maxkey = 0;
    int nbuf = 0;

    // balanced expand + process one (num,base) run per lane (chunked at LIST_CAP)
    auto process_cells = [&](int num, int base) {
        int rem = num, cur = base;
        while (true) {
            int inc = wave_scan_incl(rem, lane);
            int tot = __shfl(inc, 63, 64);
            if (tot == 0) break;
            int excl = inc - rem;
            int space = LIST_CAP - excl;
            int take = min(rem, max(space, 0));
            for (int j = 0; j < take; ++j) lst[excl + j] = cur + j;
            rem -= take; cur += take;
            int n = min(tot, LIST_CAP);
            asm volatile("s_waitcnt lgkmcnt(0)" ::: "memory");
            __builtin_amdgcn_sched_barrier(0);
            int t = lane;
            int sp_cur = (t < n) ? lst[t] : 0;
            float4 p_cur = spos[sp_cur];
            for (; t < n; t += 64) {
                int tn = t + 64;
                int sp_nx = (tn < n) ? lst[tn] : 0;
                float4 p_nx = spos[sp_nx];               // prefetch next
                float d = pdist4(qx, qy, qz, qxx, p_cur.x, p_cur.y, p_cur.z);
                int oi = __float_as_int(p_cur.w);
                unsigned long long key = ((unsigned long long)fkey(d) << 27)
                                       | ((unsigned long long)(unsigned)oi << 14)
                                       | (unsigned)sp_cur;
                if (nbuf < 16) {
                    mybuf[(size_t)nbuf * 64] = key;
                    ++nbuf;
                    minkey = (key < minkey) ? key : minkey;
                    maxkey = (key > maxkey) ? key : maxkey;
                } else if (key < maxkey) {
                    unsigned long long vmax = 0, v2 = 0;
                    int pmax = 0;
                    #pragma unroll
                    for (int j = 0; j < 16; ++j) {
                        unsigned long long v = mybuf[(size_t)j * 64];
                        if (v > vmax) { v2 = vmax; vmax = v; pmax = j; }
                        else if (v > v2) { v2 = v; }
                    }
                    mybuf[(size_t)pmax * 64] = key;
                    maxkey = (key > v2) ? key : v2;
                    minkey = (key < minkey) ? key : minkey;
                }
                sp_cur = sp_nx; p_cur = p_nx;
            }
            asm volatile("s_waitcnt lgkmcnt(0)" ::: "memory");
            __builtin_amdgcn_sched_barrier(0);
        }
    };

    // --- phase 1: full 5^3 box (Chebyshev radius <= RSTART), counts preloaded ---
    int numA[2] = {0, 0}, baseA[2] = {0, 0};
    #pragma unroll
    for (int h = 0; h < 2; ++h) {
        int u = h * 64 + lane;
        if (u < 125) {
            int dz = u / 25 - 2;
            int rm = u % 25;
            int dy = rm / 5 - 2;
            int dx = rm % 5 - 2;
            int xc = cx + dx, yc = cy + dy, zc = cz + dz;
            if ((unsigned)xc < GD && (unsigned)yc < GD && (unsigned)zc < GD) {
                int cell = (zc * GD + yc) * GD + xc;
                numA[h]  = cb[cell];
                baseA[h] = ob[cell];
            }
        }
    }
    process_cells(numA[0], baseA[0]);
    process_cells(numA[1], baseA[1]);

    // own-cell face distances; margin(R) = margin0 + R*HCELL (min(a_i)+c = min(a_i+c))
    float mlx = qx - (ORGN + (float)cx * HCELL);
    float mhx = (ORGN + (float)(cx + 1) * HCELL) - qx;
    float mly = qy - (ORGN + (float)cy * HCELL);
    float mhy = (ORGN + (float)(cy + 1) * HCELL) - qy;
    float mlz = qz - (ORGN + (float)cz * HCELL);
    float mhz = (ORGN + (float)(cz + 1) * HCELL) - qz;
    float margin0 = fminf(fminf(fminf(mlx, mhx), fminf(mly, mhy)), fminf(mlz, mhz));

    int R = RSTART;
    int brute = 0;
    unsigned long long tkey_sel = 0;
    int csel_est = 0;
    while (true) {
        // stop: >=16 candidates strictly inside the exact box-face margin (R5-proven).
        float mR  = margin0 + (float)R * HCELL;
        float mR1 = mR - HCELL;
        float mR2 = mR1 - HCELL;
        // 1e-4 shave covers fp cancellation in pdist4; negative margin -> tkey 0
        unsigned long long tk2 = (mR  > 0.f) ? ((unsigned long long)(fkey(mR  * mR  - 1e-4f) + 1u) << 27) : 0ULL;
        unsigned long long tk1 = (mR1 > 0.f) ? ((unsigned long long)(fkey(mR1 * mR1 - 1e-4f) + 1u) << 27) : 0ULL;
        unsigned long long tk0 = (mR2 > 0.f) ? ((unsigned long long)(fkey(mR2 * mR2 - 1e-4f) + 1u) << 27) : 0ULL;
        unsigned pk01 = 0;
        int c2 = 0;
        for (int j = 0; j < nbuf; ++j) {
            unsigned long long v = mybuf[(size_t)j * 64];
            pk01 += (v < tk0) ? 1u : 0u;
            pk01 += (v < tk1) ? 0x10000u : 0u;
            c2   += (v < tk2) ? 1 : 0;
        }
        for (int o = 32; o > 0; o >>= 1) {
            pk01 += __shfl_xor(pk01, o, 64);
            c2   += __shfl_xor(c2, o, 64);
        }
        if (c2 >= 16) {
            int c0 = (int)(pk01 & 0xFFFFu), c1 = (int)(pk01 >> 16);
            if      (c0 >= 16) { tkey_sel = tk0; csel_est = c0; }
            else if (c1 >= 16) { tkey_sel = tk1; csel_est = c1; }
            else               { tkey_sel = tk2; csel_est = c2; }
            break;
        }
        if (R >= RMAX_GRID) { brute = 1; break; }
        ++R;
        // scan shell R (batched; rare queries only)
        int S = 24 * R * R + 2;
        for (int u0 = 0; u0 < S; u0 += 64) {
            int u = u0 + lane;
            int num = 0, base = 0;
            if (u < S) {
                int dx, dy, dz;
                shell_decode(R, u, dx, dy, dz);
                int xc = cx + dx, yc = cy + dy, zc = cz + dz;
                if ((unsigned)xc < GD && (unsigned)yc < GD && (unsigned)zc < GD) {
                    int cell = (zc * GD + yc) * GD + xc;
                    num  = cb[cell];
                    base = ob[cell];
                }
            }
            process_cells(num, base);
        }
    }

    if (brute) {
        // exact fallback: rescan ALL points of this batch, coalesced.
        // Reset buffer so every point is seen exactly once (no duplicates).
        nbuf = 0; minkey = ~0ULL; maxkey = 0;
        int sbase = b << 13;
        for (int i = lane; i < NPTS; i += 64) {
            float4 p = spos[sbase + i];
            float d = pdist4(qx, qy, qz, qxx, p.x, p.y, p.z);
            int oi = __float_as_int(p.w);
            unsigned long long key = ((unsigned long long)fkey(d) << 27)
                                   | ((unsigned long long)(unsigned)oi << 14)
                                   | (unsigned)(sbase + i);
            if (nbuf < 16) {
                mybuf[(size_t)nbuf * 64] = key;
                ++nbuf;
                minkey = (key < minkey) ? key : minkey;
                maxkey = (key > maxkey) ? key : maxkey;
            } else if (key < maxkey) {
                unsigned long long vmax = 0, v2 = 0;
                int pmax = 0;
                #pragma unroll
                for (int j = 0; j < 16; ++j) {
                    unsigned long long v = mybuf[(size_t)j * 64];
                    if (v > vmax) { v2 = vmax; vmax = v; pmax = j; }
                    else if (v > v2) { v2 = v; }
                }
                mybuf[(size_t)pmax * 64] = key;
                maxkey = (key > v2) ? key : v2;
                minkey = (key < minkey) ? key : minkey;
            }
        }
    } else if (csel_est <= CSEL_CAP) {
        // rank-count selection fast path (order-free exact top-16 set)
        int ki = 0;
        for (int j = 0; j < nbuf; ++j) ki += (mybuf[(size_t)j * 64] < tkey_sel) ? 1 : 0;
        int incl = wave_scan_incl(ki, lane);
        int csel = __shfl(incl, 63, 64);
        unsigned long long* sel = (unsigned long long*)&lst[0];
        int w = incl - ki;
        for (int j = 0; j < nbuf; ++j) {
            unsigned long long v = mybuf[(size_t)j * 64];
            if (v < tkey_sel) sel[w++] = v;
        }
        asm volatile("s_waitcnt lgkmcnt(0)" ::: "memory");
        __builtin_amdgcn_sched_barrier(0);
        float rx = 0.f, ry = 0.f, rz = 0.f, rd = 0.f;
        for (int t = lane; t < csel; t += 64) {
            unsigned long long kt = sel[t];
            int r = 0;
            #pragma unroll 4
            for (int j = 0; j < csel; ++j) r += (sel[j] < kt) ? 1 : 0;   // broadcast reads
            if (r < 16) {
                int sp = (int)(kt & 0x3FFFu);
                int oi = (int)((kt >> 14) & 0x1FFFu);
                float4 p = spos[sp];
                float dx = p.x - qx, dy = p.y - qy, dz = p.z - qz;
                float dl = sqrtf(__fadd_rn(__fadd_rn(__fmul_rn(dx, dx), __fmul_rn(dy, dy)), __fmul_rn(dz, dz)));
                knn[(((size_t)b << 13) + nq) * 16 + r] = oi;
                rx += dx; ry += dy; rz += dz; rd += dl;
            }
        }
        for (int o = 32; o > 0; o >>= 1) {
            rx += __shfl_xor(rx, o, 64);
            ry += __shfl_xor(ry, o, 64);
            rz += __shfl_xor(rz, o, 64);
            rd += __shfl_xor(rd, o, 64);
        }
        if (lane == 0) {
            const float inv16 = 0.0625f;
            spatial[((size_t)b * 4 + 0) * NPTS + nq] = rx * inv16;
            spatial[((size_t)b * 4 + 1) * NPTS + nq] = ry * inv16;
            spatial[((size_t)b * 4 + 2) * NPTS + nq] = rz * inv16;
            spatial[((size_t)b * 4 + 3) * NPTS + nq] = rd * inv16;
        }
        return;
    }

    // fallback: exact global top-16 via 16 rounds of wave-wide u64 argmin
    unsigned long long keep = ~0ULL;
    for (int k = 0; k < 16; ++k) {
        unsigned long long m = minkey;
        for (int o = 32; o > 0; o >>= 1) {
            unsigned long long pv = shflx64(m, o);
            m = (pv < m) ? pv : m;
        }
        unsigned long long bal = __ballot(minkey == m);
        int wl = __ffsll((long long)bal) - 1;
        if (lane == wl) {
            int pos = 0;
            for (int j = 0; j < nbuf; ++j) if (mybuf[(size_t)j * 64] == m) pos = j;
            --nbuf;
            mybuf[(size_t)pos * 64] = mybuf[(size_t)nbuf * 64];
            unsigned long long nm = ~0ULL;
            for (int j = 0; j < nbuf; ++j) {
                unsigned long long v = mybuf[(size_t)j * 64];
                nm = (v < nm) ? v : nm;
            }
            minkey = nm;
        }
        if (lane == k) keep = m;
    }

    float rx = 0.f, ry = 0.f, rz = 0.f, rd = 0.f;
    if (lane < 16) {
        int sp = (int)(keep & 0x3FFFu);
        int oi = (int)((keep >> 14) & 0x1FFFu);
        float4 p = spos[sp];
        rx = p.x - qx; ry = p.y - qy; rz = p.z - qz;
        rd = sqrtf(__fadd_rn(__fadd_rn(__fmul_rn(rx, rx), __fmul_rn(ry, ry)), __fmul_rn(rz, rz)));
        knn[(((size_t)b << 13) + nq) * 16 + lane] = oi;
    }
    for (int o = 8; o > 0; o >>= 1) {
        rx += __shfl_xor(rx, o, 64);
        ry += __shfl_xor(ry, o, 64);
        rz += __shfl_xor(rz, o, 64);
        rd += __shfl_xor(rd, o, 64);
    }
    if (lane == 0) {
        const float inv16 = 0.0625f;
        spatial[((size_t)b * 4 + 0) * NPTS + nq] = rx * inv16;
        spatial[((size_t)b * 4 + 1) * NPTS + nq] = ry * inv16;
        spatial[((size_t)b * 4 + 2) * NPTS + nq] = rz * inv16;
        spatial[((size_t)b * 4 + 3) * NPTS + nq] = rd * inv16;
    }
}

// ---------------- x[B,C,N] -> xT[B,N,C] ----------------
__global__ void transpose_k(const float* __restrict__ x, float* __restrict__ xT) {
    __shared__ float tl[32][33];
    int b = blockIdx.z;
    int n0 = blockIdx.x * 32, c0 = blockIdx.y * 32;
    int tx = threadIdx.x, ty = threadIdx.y;
    const float* xb = x + (size_t)b * 128 * NN;
    float* xtb = xT + (size_t)b * NN * 128;
    for (int i = 0; i < 32; i += 8) tl[ty + i][tx] = xb[(size_t)(c0 + ty + i) * NN + n0 + tx];
    __syncthreads();
    for (int i = 0; i < 32; i += 8) xtb[(size_t)(n0 + ty + i) * 128 + c0 + tx] = tl[tx][ty + i];
}

// ---------------- max_k(x[:,idx_k]) - x  -> md[B,128,N] ----------------
__global__ __launch_bounds__(256) void md_k(const float* __restrict__ xT,
                                            const int* __restrict__ knn,
                                            float* __restrict__ md) {
    __shared__ int ki[8][16];
    __shared__ float smd[8][132];
    int b = blockIdx.y;
    int n0 = blockIdx.x * 8;
    int tid = threadIdx.x;
    if (tid < 128) ki[tid >> 4][tid & 15] = knn[(((size_t)b << 13) + n0 + (tid >> 4)) * 16 + (tid & 15)];
    __syncthreads();
    int nl = tid >> 5;
    int c4 = (tid & 31) * 4;
    const float* xb = xT + (size_t)b * NPTS * 128;
    float4 m = make_float4(-3.0e38f, -3.0e38f, -3.0e38f, -3.0e38f);
    #pragma unroll
    for (int k = 0; k < 16; ++k) {
        const float4 g = *(const float4*)(xb + (size_t)ki[nl][k] * 128 + c4);
        m.x = fmaxf(m.x, g.x); m.y = fmaxf(m.y, g.y); m.z = fmaxf(m.z, g.z); m.w = fmaxf(m.w, g.w);
    }
    const float4 own = *(const float4*)(xb + (size_t)(n0 + nl) * 128 + c4);
    m.x -= own.x; m.y -= own.y; m.z -= own.z; m.w -= own.w;
    *(float4*)(&smd[nl][c4]) = m;
    __syncthreads();
    for (int r = 0; r < 4; ++r) {
        int c = (tid >> 3) + 32 * r;
        int n2 = tid & 7;
        md[((size_t)b * 128 + c) * NN + n0 + n2] = smd[n2][c];
    }
}

// ---------------- fold conv-bias + BN into per-channel scale/shift ----------------
__global__ void prep_k(const float* bb1, const float* g1, const float* be1, const float* m1, const float* v1,
                       const float* bb2, const float* g2, const float* be2, const float* m2, const float* v2,
                       const float* sb1, const float* gs,  const float* bes, const float* ms, const float* vs,
                       const float* sb2,
                       const float* ab1, const float* ga,  const float* bea, const float* ma, const float* va,
                       const float* ab2, float* sc) {
    int t = threadIdx.x;
    if (t < 128) {
        float i1 = g1[t] / sqrtf(v1[t] + 1e-5f);
        sc[t] = i1;        sc[128 + t] = bb1[t] * i1 + be1[t] - m1[t] * i1;
        float i2 = g2[t] / sqrtf(v2[t] + 1e-5f);
        sc[256 + t] = i2;  sc[384 + t] = bb2[t] * i2 + be2[t] - m2[t] * i2;
        sc[832 + t] = 1.0f; sc[960 + t] = ab2[t];
    }
    if (t < 32) {
        float is = gs[t] / sqrtf(vs[t] + 1e-5f);
        sc[512 + t] = is;  sc[544 + t] = sb1[t] * is + bes[t] - ms[t] * is;
    }
    if (t < 64) {
        sc[576 + t] = 1.0f; sc[640 + t] = sb2[t];
        float ia = ga[t] / sqrtf(va[t] + 1e-5f);
        sc[704 + t] = ia;  sc[768 + t] = ab1[t] * ia + bea[t] - ma[t] * ia;
    }
}

// ---------------- generic 1x1-conv (+folded BN, activation) ----------------
// ACT: 0=none, 1=relu, 2=sigmoid + fused "dout = x + y2*attn"
template <int O, int K, int TILE_N, int SPLIT, int ACT>
__global__ __launch_bounds__(256) void conv_bn(const float* __restrict__ srcA,
                                               const float* __restrict__ srcB,
                                               const float* __restrict__ W,
                                               const float* __restrict__ scale,
                                               const float* __restrict__ shift,
                                               float* __restrict__ out,
                                               const float* __restrict__ resx,
                                               const float* __restrict__ y2,
                                               float* __restrict__ dout) {
    constexpr int KC  = (K < 64) ? K : 64;
    constexpr int NT4 = TILE_N / 4;
    constexpr int O4  = O / 4;
    static_assert(NT4 * O4 == 256, "thread mapping");
    __shared__ float wT[KC][O + 4];
    __shared__ float inT[KC][TILE_N];
    int tid = threadIdx.x;
    int b = blockIdx.z;
    int n0 = blockIdx.x * TILE_N;
    int n_thr = tid % NT4;          // n fastest -> coalesced stores
    int o_thr = tid / NT4;
    float acc[4][4] = {{0.f, 0.f, 0.f, 0.f}, {0.f, 0.f, 0.f, 0.f}, {0.f, 0.f, 0.f, 0.f}, {0.f, 0.f, 0.f, 0.f}};

    for (int k0 = 0; k0 < K; k0 += KC) {
        for (int idx = tid; idx < KC * O; idx += 256) {
            int cc = idx % KC;
            int o  = idx / KC;
            wT[cc][o] = W[(size_t)o * K + k0 + cc];
        }
        for (int idx = tid; idx < KC * NT4; idx += 256) {
            int cc = idx / NT4;
            int nf = idx % NT4;
            int cg = k0 + cc;
            const float* src = (cg < SPLIT)
                ? (srcA + ((size_t)b * SPLIT + cg) * NN)
                : (srcB + ((size_t)b * (K - SPLIT) + (cg - SPLIT)) * NN);
            *(float4*)(&inT[cc][nf * 4]) = *(const float4*)(src + n0 + nf * 4);
        }
        __syncthreads();
        #pragma unroll 8
        for (int c = 0; c < KC; ++c) {
            float4 wv = *(const float4*)(&wT[c][o_thr * 4]);
            float4 iv = *(const float4*)(&inT[c][n_thr * 4]);
            acc[0][0] = fmaf(wv.x, iv.x, acc[0][0]); acc[0][1] = fmaf(wv.x, iv.y, acc[0][1]);
            acc[0][2] = fmaf(wv.x, iv.z, acc[0][2]); acc[0][3] = fmaf(wv.x, iv.w, acc[0][3]);
            acc[1][0] = fmaf(wv.y, iv.x, acc[1][0]); acc[1][1] = fmaf(wv.y, iv.y, acc[1][1]);
            acc[1][2] = fmaf(wv.y, iv.z, acc[1][2]); acc[1][3] = fmaf(wv.y, iv.w, acc[1][3]);
            acc[2][0] = fmaf(wv.z, iv.x, acc[2][0]); acc[2][1] = fmaf(wv.z, iv.y, acc[2][1]);
            acc[2][2] = fmaf(wv.z, iv.z, acc[2][2]); acc[2][3] = fmaf(wv.z, iv.w, acc[2][3]);
            acc[3][0] = fmaf(wv.w, iv.x, acc[3][0]); acc[3][1] = fmaf(wv.w, iv.y, acc[3][1]);
            acc[3][2] = fmaf(wv.w, iv.z, acc[3][2]); acc[3][3] = fmaf(wv.w, iv.w, acc[3][3]);
        }
        __syncthreads();
    }
    #pragma unroll
    for (int j = 0; j < 4; ++j) {
        int o = o_thr * 4 + j;
        float scv = scale[o], shv = shift[o];
        float4 v;
        v.x = fmaf(acc[j][0], scv, shv);
        v.y = fmaf(acc[j][1], scv, shv);
        v.z = fmaf(acc[j][2], scv, shv);
        v.w = fmaf(acc[j][3], scv, shv);
        size_t obase = ((size_t)b * O + o) * NN + n0 + n_thr * 4;
        if (ACT == 1) {
            v.x = fmaxf(v.x, 0.f); v.y = fmaxf(v.y, 0.f); v.z = fmaxf(v.z, 0.f); v.w = fmaxf(v.w, 0.f);
            *(float4*)(out + obase) = v;
        } else if (ACT == 2) {
            float4 xr = *(const float4*)(resx + obase);
            float4 yr = *(const float4*)(y2 + obase);
            v.x = xr.x + yr.x / (1.f + __expf(-v.x));
            v.y = xr.y + yr.y / (1.f + __expf(-v.y));
            v.z = xr.z + yr.z / (1.f + __expf(-v.z));
            v.w = xr.w + yr.w / (1.f + __expf(-v.w));
            *(float4*)(dout + obase) = v;
        } else {
            *(float4*)(out + obase) = v;
        }
    }
}

extern "C" void kernel_launch(void* const* d_in, const int* in_sizes, int n_in,
                              void* d_out, int out_size, void* d_ws, size_t ws_size,
                              hipStream_t stream) {
    (void)in_sizes; (void)n_in; (void)out_size; (void)ws_size;
    const float* x    = (const float*)d_in[0];
    const float* xyz  = (const float*)d_in[1];
    const float* bw1  = (const float*)d_in[2];
    const float* bb1  = (const float*)d_in[3];
    const float* bn1g = (const float*)d_in[4];
    const float* bn1b = (const float*)d_in[5];
    const float* bn1m = (const float*)d_in[6];
    const float* bn1v = (const float*)d_in[7];
    const float* bw2  = (const float*)d_in[8];
    const float* bb2  = (const float*)d_in[9];
    const float* bn2g = (const float*)d_in[10];
    const float* bn2b = (const float*)d_in[11];
    const float* bn2m = (const float*)d_in[12];
    const float* bn2v = (const float*)d_in[13];
    const float* sw1  = (const float*)d_in[14];
    const float* sb1  = (const float*)d_in[15];
    const float* sbng = (const float*)d_in[16];
    const float* sbnb = (const float*)d_in[17];
    const float* sbnm = (const float*)d_in[18];
    const float* sbnv = (const float*)d_in[19];
    const float* sw2  = (const float*)d_in[20];
    const float* sb2  = (const float*)d_in[21];
    const float* aw1  = (const float*)d_in[22];
    const float* ab1  = (const float*)d_in[23];
    const float* abng = (const float*)d_in[24];
    const float* abnb = (const float*)d_in[25];
    const float* abnm = (const float*)d_in[26];
    const float* abnv = (const float*)d_in[27];
    const float* aw2  = (const float*)d_in[28];
    const float* ab2  = (const float*)d_in[29];

    char* ws = (char*)d_ws;
    int*    cnt    = (int*)(ws + OFF_CNT);
    int*    offs   = (int*)(ws + OFF_OFFS);
    int*    cellid = (int*)(ws + OFF_CELLID);
    int*    rank   = (int*)(ws + OFF_RANK);
    float4* spos   = (float4*)(ws + OFF_SPOS);
    int*    knn    = (int*)(ws + OFF_KNN);
    float*  spat   = (float*)(ws + OFF_SPATIAL);
    float*  xT     = (float*)(ws + OFF_XT);
    float*  md     = (float*)(ws + OFF_MD);
    float*  s1b    = (float*)(ws + OFF_S1);
    float*  sfb    = (float*)(ws + OFF_SF);
    float*  y1b    = (float*)(ws + OFF_Y1);
    float*  y2b    = (float*)(ws + OFF_Y2);
    float*  a1b    = (float*)(ws + OFF_A1);
    float*  sc     = (float*)(ws + OFF_SC);
    int*    bsum   = (int*)(ws + OFF_BSUM);
    int*    bpre   = (int*)(ws + OFF_BPRE);
    float*  dout   = (float*)d_out;

    hipMemsetAsync(cnt, 0, (size_t)TOTC * 4, stream);
    cell_build<<<dim3((NTOT + 255) / 256), 256, 0, stream>>>(xyz, cnt, cellid, rank);
    scan_sums<<<dim3(NBLK_SCAN), 256, 0, stream>>>(cnt, bsum);
    scan_top<<<dim3(1), 512, 0, stream>>>(bsum, bpre);
    scan_write<<<dim3(NBLK_SCAN), 256, 0, stream>>>(cnt, bpre, offs);
    scatter_k<<<dim3((NTOT + 255) / 256), 256, 0, stream>>>(xyz, cellid, rank, offs, spos);
    knn_kernel<<<dim3(NTOT), 64, 0, stream>>>(spos, cnt, offs, knn, spat);
    transpose_k<<<dim3(NPTS / 32, 128 / 32, NB), dim3(32, 8), 0, stream>>>(x, xT);
    md_k<<<dim3(NPTS / 8, NB), 256, 0, stream>>>(xT, knn, md);
    prep_k<<<1, 128, 0, stream>>>(bb1, bn1g, bn1b, bn1m, bn1v,
                                  bb2, bn2g, bn2b, bn2m, bn2v,
                                  sb1, sbng, sbnb, sbnm, sbnv,
                                  sb2,
                                  ab1, abng, abnb, abnm, abnv,
                                  ab2, sc);
    // spatial MLP: 4->32 (bn,relu), 32->64
    conv_bn<32, 4, 128, 4, 1><<<dim3(NPTS / 128, 1, NB), 256, 0, stream>>>(
        spat, spat, sw1, sc + 512, sc + 544, s1b, nullptr, nullptr, nullptr);
    conv_bn<64, 32, 64, 32, 0><<<dim3(NPTS / 64, 1, NB), 256, 0, stream>>>(
        s1b, s1b, sw2, sc + 576, sc + 640, sfb, nullptr, nullptr, nullptr);
    // boundary net: [x;md] 256->128 (bn,relu), 128->128 (bn,relu)
    conv_bn<128, 256, 32, 128, 1><<<dim3(NPTS / 32, 1, NB), 256, 0, stream>>>(
        x, md, bw1, sc + 0, sc + 128, y1b, nullptr, nullptr, nullptr);
    conv_bn<128, 128, 32, 128, 1><<<dim3(NPTS / 32, 1, NB), 256, 0, stream>>>(
        y1b, y1b, bw2, sc + 256, sc + 384, y2b, nullptr, nullptr, nullptr);
    // attention: [x;sfeat] 192->64 (bn,relu), 64->128 sigmoid + final fuse
    conv_bn<64, 192, 64, 128, 1><<<dim3(NPTS / 64, 1, NB), 256, 0, stream>>>(
        x, sfb, aw1, sc + 704, sc + 768, a1b, nullptr, nullptr, nullptr);
    conv_bn<128, 64, 32, 64, 2><<<dim3(NPTS / 32, 1, NB), 256, 0, stream>>>(
        a1b, a1b, aw2, sc + 832, sc + 960, dout, x, y2b, dout);
}

// Round 4
// 336.171 us; speedup vs baseline: 1.3462x; 1.1770x over previous
//
#include <hip/hip_runtime.h>
#include <math.h>

#define NPTS  8192
#define NB    2
#define NTOT  (NPTS*NB)
#define GD    60
#define NCELL (GD*GD*GD)
#define TOTC  (NB*NCELL)
#define HCELL 0.2f
#define INVH  5.0f
#define ORGN  (-6.0f)
#define NN    8192
#define SCAN_CHUNK 1024
#define NBLK_SCAN  ((TOTC + SCAN_CHUNK - 1) / SCAN_CHUNK)
#define RMAX_GRID 4    // beyond this radius, brute-force
#define RSTART    2    // initial full box (2*RSTART+1)^3
#define LIST_CAP 1024  // slot-expansion list (ints, 4KB)
#define SEL_CAP  1024  // appended-key list (u64, 8KB)

// ---------------- workspace layout (bytes) ----------------
#define OFF_CNT     ((size_t)0)
#define OFF_OFFS    (OFF_CNT    + (size_t)TOTC*4)
#define OFF_CELLID  (OFF_OFFS   + (size_t)TOTC*4)
#define OFF_RANK    (OFF_CELLID + (size_t)NTOT*4)
#define OFF_SPOS    (OFF_RANK   + (size_t)NTOT*4)          // float4 * NTOT (w = origidx bits)
#define OFF_KNN     (OFF_SPOS   + (size_t)NTOT*16)         // int * NTOT*16
#define OFF_SPATIAL (OFF_KNN    + (size_t)NTOT*16*4)       // [B,4,N]
#define OFF_XT      (OFF_SPATIAL+ (size_t)NB*4*NPTS*4)     // [B,N,128]
#define OFF_MD      (OFF_XT     + (size_t)NB*128*NPTS*4)   // [B,128,N]
#define OFF_S1      (OFF_MD     + (size_t)NB*128*NPTS*4)   // [B,32,N]
#define OFF_SF      (OFF_S1     + (size_t)NB*32*NPTS*4)    // [B,64,N]
#define OFF_Y1      (OFF_SF     + (size_t)NB*64*NPTS*4)    // [B,128,N]
#define OFF_Y2      (OFF_Y1     + (size_t)NB*128*NPTS*4)   // [B,128,N]
#define OFF_A1      (OFF_Y2     + (size_t)NB*128*NPTS*4)   // [B,64,N]
#define OFF_SC      (OFF_A1     + (size_t)NB*64*NPTS*4)    // 1088 floats
#define OFF_BSUM    (OFF_SC     + (size_t)1088*4)          // NBLK_SCAN ints
#define OFF_BPRE    (OFF_BSUM   + (size_t)NBLK_SCAN*4)     // NBLK_SCAN ints
#define OFF_RNG     (((OFF_BPRE + (size_t)NBLK_SCAN*4) + 15) & ~(size_t)15)  // int2 * TOTC

// Replicate reference arithmetic exactly (no fma contraction).
static __device__ __forceinline__ float sumsq3(float x, float y, float z) {
    return __fadd_rn(__fadd_rn(__fmul_rn(x, x), __fmul_rn(y, y)), __fmul_rn(z, z));
}
static __device__ __forceinline__ float pdist4(float qx, float qy, float qz, float qxx,
                                               float px, float py, float pz) {
    float pxx = sumsq3(px, py, pz);
    float dot = __fadd_rn(__fadd_rn(__fmul_rn(qx, px), __fmul_rn(qy, py)), __fmul_rn(qz, pz));
    return __fsub_rn(__fadd_rn(qxx, pxx), __fadd_rn(dot, dot));
}
// monotone unsigned key for float (handles tiny negative self-distance)
static __device__ __forceinline__ unsigned fkey(float f) {
    unsigned b = __float_as_uint(f);
    return b ^ ((unsigned)(((int)b) >> 31) | 0x80000000u);
}
static __device__ __forceinline__ unsigned long long shflx64(unsigned long long v, int m) {
    unsigned lo = __shfl_xor((unsigned)v, m, 64);
    unsigned hi = __shfl_xor((unsigned)(v >> 32), m, 64);
    return ((unsigned long long)hi << 32) | lo;
}
// inclusive wave prefix-sum (all 64 lanes active)
static __device__ __forceinline__ int wave_scan_incl(int v, int lane) {
    #pragma unroll
    for (int d = 1; d < 64; d <<= 1) {
        int u = __shfl_up(v, d, 64);
        v += (lane >= d) ? u : 0;
    }
    return v;
}

// ---------------- grid build ----------------
__global__ void cell_build(const float* __restrict__ xyz, int* __restrict__ cnt,
                           int* __restrict__ cellid, int* __restrict__ rank) {
    int t = blockIdx.x * 256 + threadIdx.x;
    if (t >= NTOT) return;
    const float* p = xyz + (size_t)t * 3;
    float x = p[0], y = p[1], z = p[2];
    int cx = min(GD - 1, max(0, (int)floorf((x - ORGN) * INVH)));
    int cy = min(GD - 1, max(0, (int)floorf((y - ORGN) * INVH)));
    int cz = min(GD - 1, max(0, (int)floorf((z - ORGN) * INVH)));
    int gcell = (t >> 13) * NCELL + (cz * GD + cy) * GD + cx;
    rank[t] = atomicAdd(&cnt[gcell], 1);
    cellid[t] = gcell;
}

// -------- hierarchical exclusive scan of cnt[TOTC] -> offs[TOTC] (+rng int2) --------
__global__ __launch_bounds__(256) void scan_sums(const int* __restrict__ cnt, int* __restrict__ bsum) {
    __shared__ int red[256];
    int blk = blockIdx.x, t = threadIdx.x;
    int i0 = blk * SCAN_CHUNK + t * 4;
    int s = 0;
    if (i0 + 3 < TOTC) {
        int4 v = *(const int4*)(cnt + i0);
        s = v.x + v.y + v.z + v.w;
    } else {
        for (int j = 0; j < 4; ++j) if (i0 + j < TOTC) s += cnt[i0 + j];
    }
    red[t] = s;
    __syncthreads();
    for (int d = 128; d > 0; d >>= 1) {
        if (t < d) red[t] += red[t + d];
        __syncthreads();
    }
    if (t == 0) bsum[blk] = red[0];
}

__global__ __launch_bounds__(512) void scan_top(const int* __restrict__ bsum, int* __restrict__ bpre) {
    __shared__ int ps[512];
    int t = threadIdx.x;
    int v = (t < NBLK_SCAN) ? bsum[t] : 0;
    ps[t] = v;
    __syncthreads();
    for (int d = 1; d < 512; d <<= 1) {
        int u = 0;
        if (t >= d) u = ps[t - d];
        __syncthreads();
        ps[t] += u;
        __syncthreads();
    }
    if (t < NBLK_SCAN) bpre[t] = ps[t] - v;   // exclusive
}

__global__ __launch_bounds__(256) void scan_write(const int* __restrict__ cnt, const int* __restrict__ bpre,
                                                  int* __restrict__ offs, int2* __restrict__ rng) {
    __shared__ int ps[256];
    int blk = blockIdx.x, t = threadIdx.x;
    int i0 = blk * SCAN_CHUNK + t * 4;
    int a = 0, b = 0, c = 0, d = 0;
    if (i0 + 3 < TOTC) {
        int4 v = *(const int4*)(cnt + i0);
        a = v.x; b = v.y; c = v.z; d = v.w;
    } else {
        if (i0 + 0 < TOTC) a = cnt[i0 + 0];
        if (i0 + 1 < TOTC) b = cnt[i0 + 1];
        if (i0 + 2 < TOTC) c = cnt[i0 + 2];
        if (i0 + 3 < TOTC) d = cnt[i0 + 3];
    }
    int s = a + b + c + d;
    ps[t] = s;
    __syncthreads();
    for (int dd = 1; dd < 256; dd <<= 1) {
        int u = 0;
        if (t >= dd) u = ps[t - dd];
        __syncthreads();
        ps[t] += u;
        __syncthreads();
    }
    int base = bpre[blk] + ps[t] - s;
    if (i0 + 3 < TOTC) {
        offs[i0 + 0] = base;
        offs[i0 + 1] = base + a;
        offs[i0 + 2] = base + a + b;
        offs[i0 + 3] = base + a + b + c;
        *(int4*)(rng + i0)     = make_int4(base, base + a, base + a, base + a + b);
        *(int4*)(rng + i0 + 2) = make_int4(base + a + b, base + a + b + c,
                                           base + a + b + c, base + s);
    } else {
        if (i0 + 0 < TOTC) { offs[i0 + 0] = base;             rng[i0 + 0] = make_int2(base, base + a); }
        if (i0 + 1 < TOTC) { offs[i0 + 1] = base + a;         rng[i0 + 1] = make_int2(base + a, base + a + b); }
        if (i0 + 2 < TOTC) { offs[i0 + 2] = base + a + b;     rng[i0 + 2] = make_int2(base + a + b, base + a + b + c); }
        if (i0 + 3 < TOTC) { offs[i0 + 3] = base + a + b + c; rng[i0 + 3] = make_int2(base + a + b + c, base + s); }
    }
}

__global__ void scatter_k(const float* __restrict__ xyz, const int* __restrict__ cellid,
                          const int* __restrict__ rank, const int* __restrict__ offs,
                          float4* __restrict__ spos) {
    int t = blockIdx.x * 256 + threadIdx.x;
    if (t >= NTOT) return;
    const float* p = xyz + (size_t)t * 3;
    float x = p[0], y = p[1], z = p[2];
    int pos = offs[cellid[t]] + rank[t];
    spos[pos] = make_float4(x, y, z, __int_as_float(t & (NPTS - 1)));
}

// ---------------- exact KNN: one wave per query, append-threshold design ----------------
// R10: (a) rng row-runs (points sorted by cell -> each (dz,dy) row is one contiguous
// slot run; 2 gathers per row instead of per-cell cnt/offs). (b) NO per-lane top-16
// maintenance: every candidate with key < tk(margin0+(RMAX+1)h) is ballot-appended to
// a shared LDS list. Stop-check at R counts appended keys < tk(margin0+R*h) (R5-proven
// margin certification: ball(m) inside box(R) and every point with key<tk appended).
// Escalation appends only the new Chebyshev shell (fixed append threshold covers all
// stop levels <= RMAX -> no rescans). Select: compact tightest level with >=16 keys,
// rank-count (R8-proven: rank among certified-complete set = global rank).
// (c) brute tail: two-pass ladder (count 16 geometric radii; append keys under the
// tightest level with >=16; same rank-count). Per-lane-top16 brute kept only as
// ultra-rare capacity fallback.
__global__ __launch_bounds__(64) void knn_kernel(const float4* __restrict__ spos,
                                                 const int2* __restrict__ rng,
                                                 int* __restrict__ knn,
                                                 float* __restrict__ spatial) {
    __shared__ __align__(16) char shraw[12288];
    int* lst = (int*)shraw;                                        // 1024 ints (dead after scans)
    unsigned long long* sel = (unsigned long long*)(shraw + 4096); // 1024 u64
    int lane = threadIdx.x;
    int bid  = blockIdx.x;
    int s = (bid & 7) * (NTOT / 8) + (bid >> 3);   // XCD-chunked: contiguous sorted range per XCD
    float4 q = spos[s];
    float qx = q.x, qy = q.y, qz = q.z;
    float qxx = sumsq3(qx, qy, qz);
    int b  = s >> 13;
    int nq = __float_as_int(q.w);
    int cx = min(GD - 1, max(0, (int)floorf((qx - ORGN) * INVH)));
    int cy = min(GD - 1, max(0, (int)floorf((qy - ORGN) * INVH)));
    int cz = min(GD - 1, max(0, (int)floorf((qz - ORGN) * INVH)));
    const int2* rg = rng + b * NCELL;

    // own-cell face distances; margin(R) = margin0 + R*HCELL
    float mlx = qx - (ORGN + (float)cx * HCELL);
    float mhx = (ORGN + (float)(cx + 1) * HCELL) - qx;
    float mly = qy - (ORGN + (float)cy * HCELL);
    float mhy = (ORGN + (float)(cy + 1) * HCELL) - qy;
    float mlz = qz - (ORGN + (float)cz * HCELL);
    float mhz = (ORGN + (float)(cz + 1) * HCELL) - qz;
    float margin0 = fminf(fminf(fminf(mlx, mhx), fminf(mly, mhy)), fminf(mlz, mhz));

    // fixed append threshold: covers every stop level up to RMAX_GRID
    float mfin = margin0 + (float)(RMAX_GRID + 1) * HCELL;
    unsigned long long tkfin = (mfin > 0.f)
        ? ((unsigned long long)(fkey(mfin * mfin - 1e-4f) + 1u) << 27) : 0ULL;

    int tot = 0, ovf = 0;

    auto scan_runs = [&](int num, int start) {
        int rem = num, cur = start;
        for (;;) {
            int inc = wave_scan_incl(rem, lane);
            int ctot = __shfl(inc, 63, 64);
            if (ctot == 0) break;
            int excl = inc - rem;
            int space = LIST_CAP - excl;
            int take = min(rem, max(space, 0));
            for (int j = 0; j < take; ++j) lst[excl + j] = cur + j;
            rem -= take; cur += take;
            int n = min(ctot, LIST_CAP);
            asm volatile("s_waitcnt lgkmcnt(0)" ::: "memory");
            __builtin_amdgcn_sched_barrier(0);
            int sp_cur = (lane < n) ? lst[lane] : 0;
            float4 p_cur = spos[sp_cur];
            for (int t0 = 0; t0 < n; t0 += 64) {          // uniform loop: ballot-safe
                int tt = t0 + lane, tn = tt + 64;
                int sp_nx = (tn < n) ? lst[tn] : 0;
                float4 p_nx = spos[sp_nx];                 // 1-deep prefetch
                unsigned long long key = ~0ULL;
                if (tt < n) {
                    float d = pdist4(qx, qy, qz, qxx, p_cur.x, p_cur.y, p_cur.z);
                    key = ((unsigned long long)fkey(d) << 27)
                        | ((unsigned long long)(unsigned)__float_as_int(p_cur.w) << 14)
                        | (unsigned)sp_cur;
                }
                bool pass = (tt < n) && (key < tkfin);
                unsigned long long mk = __ballot(pass);
                int cnum = (int)__popcll(mk);
                if (tot + cnum > SEL_CAP) { ovf = 1; return; }
                if (pass) sel[tot + (int)__popcll(mk & ((1ULL << lane) - 1ULL))] = key;
                tot += cnum;
                sp_cur = sp_nx; p_cur = p_nx;
            }
            asm volatile("s_waitcnt lgkmcnt(0)" ::: "memory");
            __builtin_amdgcn_sched_barrier(0);
        }
    };

    int brute = (tkfin == 0ULL) ? 1 : 0;   // edge-clamped outliers straight to brute

    if (!brute) {
        // phase 1: full box R<=RSTART as 25 row-runs
        int Lb = 2 * RSTART + 1;
        int nrows = Lb * Lb;
        int num = 0, start = 0;
        if (lane < nrows) {
            int dzr = lane / Lb - RSTART, dyr = lane % Lb - RSTART;
            int zc = cz + dzr, yc = cy + dyr;
            if ((unsigned)zc < GD && (unsigned)yc < GD) {
                int rowb = (zc * GD + yc) * GD;
                int xlo = max(cx - RSTART, 0), xhi = min(cx + RSTART, GD - 1);
                start = rg[rowb + xlo].x;
                num   = rg[rowb + xhi].y - start;
            }
        }
        scan_runs(num, start);
        if (ovf) brute = 1;
    }

    int R = RSTART;
    unsigned long long tkey_sel = ~0ULL;
    int cselq = 0;
    while (!brute) {
        // stop-check at margins R, R-1, R-2 (R9-proven formulas)
        float mR  = margin0 + (float)R * HCELL;
        float mR1 = mR - HCELL, mR2 = mR1 - HCELL;
        unsigned long long tk2 = (mR  > 0.f) ? ((unsigned long long)(fkey(mR  * mR  - 1e-4f) + 1u) << 27) : 0ULL;
        unsigned long long tk1 = (mR1 > 0.f) ? ((unsigned long long)(fkey(mR1 * mR1 - 1e-4f) + 1u) << 27) : 0ULL;
        unsigned long long tk0 = (mR2 > 0.f) ? ((unsigned long long)(fkey(mR2 * mR2 - 1e-4f) + 1u) << 27) : 0ULL;
        unsigned pk01 = 0; int c2 = 0;
        for (int t0 = 0; t0 < tot; t0 += 64) {
            int tt = t0 + lane;
            if (tt < tot) {
                unsigned long long v = sel[tt];
                pk01 += (v < tk0) ? 1u : 0u;
                pk01 += (v < tk1) ? 0x10000u : 0u;
                c2   += (v < tk2) ? 1 : 0;
            }
        }
        for (int o = 32; o > 0; o >>= 1) { pk01 += __shfl_xor(pk01, o, 64); c2 += __shfl_xor(c2, o, 64); }
        if (c2 >= 16) {
            int c0 = (int)(pk01 & 0xFFFFu), c1 = (int)(pk01 >> 16);
            if      (c0 >= 16) { tkey_sel = tk0; cselq = c0; }
            else if (c1 >= 16) { tkey_sel = tk1; cselq = c1; }
            else               { tkey_sel = tk2; cselq = c2; }
            break;
        }
        if (R >= RMAX_GRID) { brute = 1; break; }
        ++R;
        // scan shell R: outer rows full x-range; inner rows two single-cell stubs
        int Ls = 2 * R + 1;
        int P = Ls * Ls, P2 = (Ls - 2) * (Ls - 2);
        int nruns = P + P2;
        for (int r0 = 0; r0 < nruns && !ovf; r0 += 64) {
            int u = r0 + lane;
            int num = 0, start = 0;
            if (u < nruns) {
                int dzr, dyr, xlo, xhi;
                if (u < P) {
                    dzr = u / Ls - R; dyr = u % Ls - R;
                    bool outer = (dzr == -R || dzr == R || dyr == -R || dyr == R);
                    if (outer) { xlo = max(cx - R, 0); xhi = min(cx + R, GD - 1); }
                    else       { xlo = cx - R; xhi = cx - R; }
                } else {
                    int v = u - P; int L2 = Ls - 2;
                    dzr = v / L2 - (R - 1); dyr = v % L2 - (R - 1);
                    xlo = cx + R; xhi = cx + R;
                }
                int zc = cz + dzr, yc = cy + dyr;
                if ((unsigned)zc < GD && (unsigned)yc < GD && xlo >= 0 && xhi < GD) {
                    int rowb = (zc * GD + yc) * GD;
                    start = rg[rowb + xlo].x;
                    num   = rg[rowb + xhi].y - start;
                }
            }
            scan_runs(num, start);
        }
        if (ovf) brute = 1;
    }

    if (brute) {
        // two-pass ladder brute over all NPTS of this batch (coalesced, regular)
        const float LADR[16] = {0.35f, 0.4725f, 0.637875f, 0.86113125f,
                                1.1625272f, 1.5694117f, 2.1187058f, 2.8602529f,
                                3.8613414f, 5.2128109f, 7.0372947f, 9.5003478f,
                                12.825470f, 17.314384f, 23.374418f, 31.555464f};
        int sbase = b << 13;
        int cc[16];
        #pragma unroll
        for (int k = 0; k < 16; ++k) cc[k] = 0;
        for (int i0 = 0; i0 < NPTS; i0 += 64) {
            float4 p = spos[sbase + i0 + lane];
            float d = pdist4(qx, qy, qz, qxx, p.x, p.y, p.z);
            #pragma unroll
            for (int k = 0; k < 16; ++k) cc[k] += (d < LADR[k] * LADR[k]) ? 1 : 0;
        }
        #pragma unroll
        for (int k = 0; k < 16; ++k)
            for (int o = 32; o > 0; o >>= 1) cc[k] += __shfl_xor(cc[k], o, 64);
        float Tq = LADR[15] * LADR[15]; int cL = cc[15];
        #pragma unroll
        for (int k = 14; k >= 0; --k) if (cc[k] >= 16) { Tq = LADR[k] * LADR[k]; cL = cc[k]; }
        if (cL <= SEL_CAP) {
            tot = 0;
            for (int i0 = 0; i0 < NPTS; i0 += 64) {
                int idx = sbase + i0 + lane;
                float4 p = spos[idx];
                float d = pdist4(qx, qy, qz, qxx, p.x, p.y, p.z);
                bool pass = (d < Tq);
                unsigned long long key = ((unsigned long long)fkey(d) << 27)
                                       | ((unsigned long long)(unsigned)__float_as_int(p.w) << 14)
                                       | (unsigned)idx;
                unsigned long long mk = __ballot(pass);
                if (pass) sel[tot + (int)__popcll(mk & ((1ULL << lane) - 1ULL))] = key;
                tot += (int)__popcll(mk);
            }
            tkey_sel = ~0ULL;   // all appended keys are candidates
            cselq = tot;
        } else {
            // ultra-rare capacity fallback: per-lane top16 in LDS + 16-round extract (R9)
            unsigned long long* mybuf = ((unsigned long long*)shraw) + lane;  // j at [j*64]
            unsigned long long minkey = ~0ULL, maxkey = 0;
            int nbuf = 0;
            for (int i = lane; i < NPTS; i += 64) {
                float4 p = spos[sbase + i];
                float d = pdist4(qx, qy, qz, qxx, p.x, p.y, p.z);
                unsigned long long key = ((unsigned long long)fkey(d) << 27)
                                       | ((unsigned long long)(unsigned)__float_as_int(p.w) << 14)
                                       | (unsigned)(sbase + i);
                if (nbuf < 16) {
                    mybuf[(size_t)nbuf * 64] = key;
                    ++nbuf;
                    minkey = (key < minkey) ? key : minkey;
                    maxkey = (key > maxkey) ? key : maxkey;
                } else if (key < maxkey) {
                    unsigned long long vmax = 0, v2 = 0;
                    int pmax = 0;
                    #pragma unroll
                    for (int j = 0; j < 16; ++j) {
                        unsigned long long v = mybuf[(size_t)j * 64];
                        if (v > vmax) { v2 = vmax; vmax = v; pmax = j; }
                        else if (v > v2) { v2 = v; }
                    }
                    mybuf[(size_t)pmax * 64] = key;
                    maxkey = (key > v2) ? key : v2;
                    minkey = (key < minkey) ? key : minkey;
                }
            }
            unsigned long long keep = ~0ULL;
            for (int k = 0; k < 16; ++k) {
                unsigned long long m = minkey;
                for (int o = 32; o > 0; o >>= 1) {
                    unsigned long long pv = shflx64(m, o);
                    m = (pv < m) ? pv : m;
                }
                unsigned long long bal = __ballot(minkey == m);
                int wl = __ffsll((long long)bal) - 1;
                if (lane == wl) {
                    int pos = 0;
                    for (int j = 0; j < nbuf; ++j) if (mybuf[(size_t)j * 64] == m) pos = j;
                    --nbuf;
                    mybuf[(size_t)pos * 64] = mybuf[(size_t)nbuf * 64];
                    unsigned long long nm = ~0ULL;
                    for (int j = 0; j < nbuf; ++j) {
                        unsigned long long v = mybuf[(size_t)j * 64];
                        nm = (v < nm) ? v : nm;
                    }
                    minkey = nm;
                }
                if (lane == k) keep = m;
            }
            float rx = 0.f, ry = 0.f, rz = 0.f, rd = 0.f;
            if (lane < 16) {
                int sp = (int)(keep & 0x3FFFu);
                int oi = (int)((keep >> 14) & 0x1FFFu);
                float4 p = spos[sp];
                rx = p.x - qx; ry = p.y - qy; rz = p.z - qz;
                rd = sqrtf(__fadd_rn(__fadd_rn(__fmul_rn(rx, rx), __fmul_rn(ry, ry)), __fmul_rn(rz, rz)));
                knn[(((size_t)b << 13) + nq) * 16 + lane] = oi;
            }
            for (int o = 8; o > 0; o >>= 1) {
                rx += __shfl_xor(rx, o, 64);
                ry += __shfl_xor(ry, o, 64);
                rz += __shfl_xor(rz, o, 64);
                rd += __shfl_xor(rd, o, 64);
            }
            if (lane == 0) {
                const float inv16 = 0.0625f;
                spatial[((size_t)b * 4 + 0) * NPTS + nq] = rx * inv16;
                spatial[((size_t)b * 4 + 1) * NPTS + nq] = ry * inv16;
                spatial[((size_t)b * 4 + 2) * NPTS + nq] = rz * inv16;
                spatial[((size_t)b * 4 + 3) * NPTS + nq] = rd * inv16;
            }
            return;
        }
    }

    // -------- shared selection: compact keys < tkey_sel, then rank-count --------
    asm volatile("s_waitcnt lgkmcnt(0)" ::: "memory");
    __builtin_amdgcn_sched_barrier(0);
    unsigned long long* sel2 = (unsigned long long*)shraw;   // reuse lst region (512 u64)
    const unsigned long long* src;
    int m;
    if (cselq <= 512) {
        int w = 0;
        for (int t0 = 0; t0 < tot; t0 += 64) {
            int tt = t0 + lane;
            unsigned long long v = (tt < tot) ? sel[tt] : ~0ULL;
            bool pass = (tt < tot) && (v < tkey_sel);
            unsigned long long mk = __ballot(pass);
            if (pass) sel2[w + (int)__popcll(mk & ((1ULL << lane) - 1ULL))] = v;
            w += (int)__popcll(mk);
        }
        asm volatile("s_waitcnt lgkmcnt(0)" ::: "memory");
        __builtin_amdgcn_sched_barrier(0);
        src = sel2; m = w;
    } else {
        src = sel; m = tot;   // rare slow path: rank directly with predicate
    }
    float rxs = 0.f, rys = 0.f, rzs = 0.f, rds = 0.f;
    for (int t0 = 0; t0 < m; t0 += 64) {
        int tt = t0 + lane;
        if (tt < m) {
            unsigned long long kt = src[tt];
            if (kt < tkey_sel) {
                int rr = 0;
                for (int j = 0; j < m; ++j) rr += (src[j] < kt) ? 1 : 0;   // broadcast reads
                if (rr < 16) {
                    int sp = (int)(kt & 0x3FFFu);
                    int oi = (int)((kt >> 14) & 0x1FFFu);
                    float4 p = spos[sp];
                    float dx = p.x - qx, dy = p.y - qy, dz = p.z - qz;
                    float dl = sqrtf(__fadd_rn(__fadd_rn(__fmul_rn(dx, dx), __fmul_rn(dy, dy)), __fmul_rn(dz, dz)));
                    knn[(((size_t)b << 13) + nq) * 16 + rr] = oi;
                    rxs += dx; rys += dy; rzs += dz; rds += dl;
                }
            }
        }
    }
    for (int o = 32; o > 0; o >>= 1) {
        rxs += __shfl_xor(rxs, o, 64);
        rys += __shfl_xor(rys, o, 64);
        rzs += __shfl_xor(rzs, o, 64);
        rds += __shfl_xor(rds, o, 64);
    }
    if (lane == 0) {
        const float inv16 = 0.0625f;
        spatial[((size_t)b * 4 + 0) * NPTS + nq] = rxs * inv16;
        spatial[((size_t)b * 4 + 1) * NPTS + nq] = rys * inv16;
        spatial[((size_t)b * 4 + 2) * NPTS + nq] = rzs * inv16;
        spatial[((size_t)b * 4 + 3) * NPTS + nq] = rds * inv16;
    }
}

// ---------------- x[B,C,N] -> xT[B,N,C] ----------------
__global__ void transpose_k(const float* __restrict__ x, float* __restrict__ xT) {
    __shared__ float tl[32][33];
    int b = blockIdx.z;
    int n0 = blockIdx.x * 32, c0 = blockIdx.y * 32;
    int tx = threadIdx.x, ty = threadIdx.y;
    const float* xb = x + (size_t)b * 128 * NN;
    float* xtb = xT + (size_t)b * NN * 128;
    for (int i = 0; i < 32; i += 8) tl[ty + i][tx] = xb[(size_t)(c0 + ty + i) * NN + n0 + tx];
    __syncthreads();
    for (int i = 0; i < 32; i += 8) xtb[(size_t)(n0 + ty + i) * 128 + c0 + tx] = tl[tx][ty + i];
}

// ---------------- max_k(x[:,idx_k]) - x  -> md[B,128,N] ----------------
__global__ __launch_bounds__(256) void md_k(const float* __restrict__ xT,
                                            const int* __restrict__ knn,
                                            float* __restrict__ md) {
    __shared__ int ki[8][16];
    __shared__ float smd[8][132];
    int b = blockIdx.y;
    int n0 = blockIdx.x * 8;
    int tid = threadIdx.x;
    if (tid < 128) ki[tid >> 4][tid & 15] = knn[(((size_t)b << 13) + n0 + (tid >> 4)) * 16 + (tid & 15)];
    __syncthreads();
    int nl = tid >> 5;
    int c4 = (tid & 31) * 4;
    const float* xb = xT + (size_t)b * NPTS * 128;
    float4 m = make_float4(-3.0e38f, -3.0e38f, -3.0e38f, -3.0e38f);
    #pragma unroll
    for (int k = 0; k < 16; ++k) {
        const float4 g = *(const float4*)(xb + (size_t)ki[nl][k] * 128 + c4);
        m.x = fmaxf(m.x, g.x); m.y = fmaxf(m.y, g.y); m.z = fmaxf(m.z, g.z); m.w = fmaxf(m.w, g.w);
    }
    const float4 own = *(const float4*)(xb + (size_t)(n0 + nl) * 128 + c4);
    m.x -= own.x; m.y -= own.y; m.z -= own.z; m.w -= own.w;
    *(float4*)(&smd[nl][c4]) = m;
    __syncthreads();
    for (int r = 0; r < 4; ++r) {
        int c = (tid >> 3) + 32 * r;
        int n2 = tid & 7;
        md[((size_t)b * 128 + c) * NN + n0 + n2] = smd[n2][c];
    }
}

// ---------------- fold conv-bias + BN into per-channel scale/shift ----------------
__global__ void prep_k(const float* bb1, const float* g1, const float* be1, const float* m1, const float* v1,
                       const float* bb2, const float* g2, const float* be2, const float* m2, const float* v2,
                       const float* sb1, const float* gs,  const float* bes, const float* ms, const float* vs,
                       const float* sb2,
                       const float* ab1, const float* ga,  const float* bea, const float* ma, const float* va,
                       const float* ab2, float* sc) {
    int t = threadIdx.x;
    if (t < 128) {
        float i1 = g1[t] / sqrtf(v1[t] + 1e-5f);
        sc[t] = i1;        sc[128 + t] = bb1[t] * i1 + be1[t] - m1[t] * i1;
        float i2 = g2[t] / sqrtf(v2[t] + 1e-5f);
        sc[256 + t] = i2;  sc[384 + t] = bb2[t] * i2 + be2[t] - m2[t] * i2;
        sc[832 + t] = 1.0f; sc[960 + t] = ab2[t];
    }
    if (t < 32) {
        float is = gs[t] / sqrtf(vs[t] + 1e-5f);
        sc[512 + t] = is;  sc[544 + t] = sb1[t] * is + bes[t] - ms[t] * is;
    }
    if (t < 64) {
        sc[576 + t] = 1.0f; sc[640 + t] = sb2[t];
        float ia = ga[t] / sqrtf(va[t] + 1e-5f);
        sc[704 + t] = ia;  sc[768 + t] = ab1[t] * ia + bea[t] - ma[t] * ia;
    }
}

// ---------------- generic 1x1-conv (+folded BN, activation) ----------------
// ACT: 0=none, 1=relu, 2=sigmoid + fused "dout = x + y2*attn"
template <int O, int K, int TILE_N, int SPLIT, int ACT>
__global__ __launch_bounds__(256) void conv_bn(const float* __restrict__ srcA,
                                               const float* __restrict__ srcB,
                                               const float* __restrict__ W,
                                               const float* __restrict__ scale,
                                               const float* __restrict__ shift,
                                               float* __restrict__ out,
                                               const float* __restrict__ resx,
                                               const float* __restrict__ y2,
                                               float* __restrict__ dout) {
    constexpr int KC  = (K < 64) ? K : 64;
    constexpr int NT4 = TILE_N / 4;
    constexpr int O4  = O / 4;
    static_assert(NT4 * O4 == 256, "thread mapping");
    __shared__ float wT[KC][O + 4];
    __shared__ float inT[KC][TILE_N];
    int tid = threadIdx.x;
    int b = blockIdx.z;
    int n0 = blockIdx.x * TILE_N;
    int n_thr = tid % NT4;          // n fastest -> coalesced stores
    int o_thr = tid / NT4;
    float acc[4][4] = {{0.f, 0.f, 0.f, 0.f}, {0.f, 0.f, 0.f, 0.f}, {0.f, 0.f, 0.f, 0.f}, {0.f, 0.f, 0.f, 0.f}};

    for (int k0 = 0; k0 < K; k0 += KC) {
        for (int idx = tid; idx < KC * O; idx += 256) {
            int cc = idx % KC;
            int o  = idx / KC;
            wT[cc][o] = W[(size_t)o * K + k0 + cc];
        }
        for (int idx = tid; idx < KC * NT4; idx += 256) {
            int cc = idx / NT4;
            int nf = idx % NT4;
            int cg = k0 + cc;
            const float* src = (cg < SPLIT)
                ? (srcA + ((size_t)b * SPLIT + cg) * NN)
                : (srcB + ((size_t)b * (K - SPLIT) + (cg - SPLIT)) * NN);
            *(float4*)(&inT[cc][nf * 4]) = *(const float4*)(src + n0 + nf * 4);
        }
        __syncthreads();
        #pragma unroll 8
        for (int c = 0; c < KC; ++c) {
            float4 wv = *(const float4*)(&wT[c][o_thr * 4]);
            float4 iv = *(const float4*)(&inT[c][n_thr * 4]);
            acc[0][0] = fmaf(wv.x, iv.x, acc[0][0]); acc[0][1] = fmaf(wv.x, iv.y, acc[0][1]);
            acc[0][2] = fmaf(wv.x, iv.z, acc[0][2]); acc[0][3] = fmaf(wv.x, iv.w, acc[0][3]);
            acc[1][0] = fmaf(wv.y, iv.x, acc[1][0]); acc[1][1] = fmaf(wv.y, iv.y, acc[1][1]);
            acc[1][2] = fmaf(wv.y, iv.z, acc[1][2]); acc[1][3] = fmaf(wv.y, iv.w, acc[1][3]);
            acc[2][0] = fmaf(wv.z, iv.x, acc[2][0]); acc[2][1] = fmaf(wv.z, iv.y, acc[2][1]);
            acc[2][2] = fmaf(wv.z, iv.z, acc[2][2]); acc[2][3] = fmaf(wv.z, iv.w, acc[2][3]);
            acc[3][0] = fmaf(wv.w, iv.x, acc[3][0]); acc[3][1] = fmaf(wv.w, iv.y, acc[3][1]);
            acc[3][2] = fmaf(wv.w, iv.z, acc[3][2]); acc[3][3] = fmaf(wv.w, iv.w, acc[3][3]);
        }
        __syncthreads();
    }
    #pragma unroll
    for (int j = 0; j < 4; ++j) {
        int o = o_thr * 4 + j;
        float scv = scale[o], shv = shift[o];
        float4 v;
        v.x = fmaf(acc[j][0], scv, shv);
        v.y = fmaf(acc[j][1], scv, shv);
        v.z = fmaf(acc[j][2], scv, shv);
        v.w = fmaf(acc[j][3], scv, shv);
        size_t obase = ((size_t)b * O + o) * NN + n0 + n_thr * 4;
        if (ACT == 1) {
            v.x = fmaxf(v.x, 0.f); v.y = fmaxf(v.y, 0.f); v.z = fmaxf(v.z, 0.f); v.w = fmaxf(v.w, 0.f);
            *(float4*)(out + obase) = v;
        } else if (ACT == 2) {
            float4 xr = *(const float4*)(resx + obase);
            float4 yr = *(const float4*)(y2 + obase);
            v.x = xr.x + yr.x / (1.f + __expf(-v.x));
            v.y = xr.y + yr.y / (1.f + __expf(-v.y));
            v.z = xr.z + yr.z / (1.f + __expf(-v.z));
            v.w = xr.w + yr.w / (1.f + __expf(-v.w));
            *(float4*)(dout + obase) = v;
        } else {
            *(float4*)(out + obase) = v;
        }
    }
}

extern "C" void kernel_launch(void* const* d_in, const int* in_sizes, int n_in,
                              void* d_out, int out_size, void* d_ws, size_t ws_size,
                              hipStream_t stream) {
    (void)in_sizes; (void)n_in; (void)out_size; (void)ws_size;
    const float* x    = (const float*)d_in[0];
    const float* xyz  = (const float*)d_in[1];
    const float* bw1  = (const float*)d_in[2];
    const float* bb1  = (const float*)d_in[3];
    const float* bn1g = (const float*)d_in[4];
    const float* bn1b = (const float*)d_in[5];
    const float* bn1m = (const float*)d_in[6];
    const float* bn1v = (const float*)d_in[7];
    const float* bw2  = (const float*)d_in[8];
    const float* bb2  = (const float*)d_in[9];
    const float* bn2g = (const float*)d_in[10];
    const float* bn2b = (const float*)d_in[11];
    const float* bn2m = (const float*)d_in[12];
    const float* bn2v = (const float*)d_in[13];
    const float* sw1  = (const float*)d_in[14];
    const float* sb1  = (const float*)d_in[15];
    const float* sbng = (const float*)d_in[16];
    const float* sbnb = (const float*)d_in[17];
    const float* sbnm = (const float*)d_in[18];
    const float* sbnv = (const float*)d_in[19];
    const float* sw2  = (const float*)d_in[20];
    const float* sb2  = (const float*)d_in[21];
    const float* aw1  = (const float*)d_in[22];
    const float* ab1  = (const float*)d_in[23];
    const float* abng = (const float*)d_in[24];
    const float* abnb = (const float*)d_in[25];
    const float* abnm = (const float*)d_in[26];
    const float* abnv = (const float*)d_in[27];
    const float* aw2  = (const float*)d_in[28];
    const float* ab2  = (const float*)d_in[29];

    char* ws = (char*)d_ws;
    int*    cnt    = (int*)(ws + OFF_CNT);
    int*    offs   = (int*)(ws + OFF_OFFS);
    int*    cellid = (int*)(ws + OFF_CELLID);
    int*    rank   = (int*)(ws + OFF_RANK);
    float4* spos   = (float4*)(ws + OFF_SPOS);
    int*    knn    = (int*)(ws + OFF_KNN);
    float*  spat   = (float*)(ws + OFF_SPATIAL);
    float*  xT     = (float*)(ws + OFF_XT);
    float*  md     = (float*)(ws + OFF_MD);
    float*  s1b    = (float*)(ws + OFF_S1);
    float*  sfb    = (float*)(ws + OFF_SF);
    float*  y1b    = (float*)(ws + OFF_Y1);
    float*  y2b    = (float*)(ws + OFF_Y2);
    float*  a1b    = (float*)(ws + OFF_A1);
    float*  sc     = (float*)(ws + OFF_SC);
    int*    bsum   = (int*)(ws + OFF_BSUM);
    int*    bpre   = (int*)(ws + OFF_BPRE);
    int2*   rng    = (int2*)(ws + OFF_RNG);
    float*  dout   = (float*)d_out;

    hipMemsetAsync(cnt, 0, (size_t)TOTC * 4, stream);
    cell_build<<<dim3((NTOT + 255) / 256), 256, 0, stream>>>(xyz, cnt, cellid, rank);
    scan_sums<<<dim3(NBLK_SCAN), 256, 0, stream>>>(cnt, bsum);
    scan_top<<<dim3(1), 512, 0, stream>>>(bsum, bpre);
    scan_write<<<dim3(NBLK_SCAN), 256, 0, stream>>>(cnt, bpre, offs, rng);
    scatter_k<<<dim3((NTOT + 255) / 256), 256, 0, stream>>>(xyz, cellid, rank, offs, spos);
    knn_kernel<<<dim3(NTOT), 64, 0, stream>>>(spos, rng, knn, spat);
    transpose_k<<<dim3(NPTS / 32, 128 / 32, NB), dim3(32, 8), 0, stream>>>(x, xT);
    md_k<<<dim3(NPTS / 8, NB), 256, 0, stream>>>(xT, knn, md);
    prep_k<<<1, 128, 0, stream>>>(bb1, bn1g, bn1b, bn1m, bn1v,
                                  bb2, bn2g, bn2b, bn2m, bn2v,
                                  sb1, sbng, sbnb, sbnm, sbnv,
                                  sb2,
                                  ab1, abng, abnb, abnm, abnv,
                                  ab2, sc);
    // spatial MLP: 4->32 (bn,relu), 32->64
    conv_bn<32, 4, 128, 4, 1><<<dim3(NPTS / 128, 1, NB), 256, 0, stream>>>(
        spat, spat, sw1, sc + 512, sc + 544, s1b, nullptr, nullptr, nullptr);
    conv_bn<64, 32, 64, 32, 0><<<dim3(NPTS / 64, 1, NB), 256, 0, stream>>>(
        s1b, s1b, sw2, sc + 576, sc + 640, sfb, nullptr, nullptr, nullptr);
    // boundary net: [x;md] 256->128 (bn,relu), 128->128 (bn,relu)
    conv_bn<128, 256, 32, 128, 1><<<dim3(NPTS / 32, 1, NB), 256, 0, stream>>>(
        x, md, bw1, sc + 0, sc + 128, y1b, nullptr, nullptr, nullptr);
    conv_bn<128, 128, 32, 128, 1><<<dim3(NPTS / 32, 1, NB), 256, 0, stream>>>(
        y1b, y1b, bw2, sc + 256, sc + 384, y2b, nullptr, nullptr, nullptr);
    // attention: [x;sfeat] 192->64 (bn,relu), 64->128 sigmoid + final fuse
    conv_bn<64, 192, 64, 128, 1><<<dim3(NPTS / 64, 1, NB), 256, 0, stream>>>(
        x, sfb, aw1, sc + 704, sc + 768, a1b, nullptr, nullptr, nullptr);
    conv_bn<128, 64, 32, 64, 2><<<dim3(NPTS / 32, 1, NB), 256, 0, stream>>>(
        a1b, a1b, aw2, sc + 832, sc + 960, dout, x, y2b, dout);
}

// Round 5
// 326.036 us; speedup vs baseline: 1.3881x; 1.0311x over previous
//
#include <hip/hip_runtime.h>
#include <math.h>

#define NPTS  8192
#define NB    2
#define NTOT  (NPTS*NB)
#define GD    60
#define NCELL (GD*GD*GD)
#define TOTC  (NB*NCELL)
#define HCELL 0.2f
#define INVH  5.0f
#define ORGN  (-6.0f)
#define NN    8192
#define SCAN_CHUNK 1024
#define NBLK_SCAN  ((TOTC + SCAN_CHUNK - 1) / SCAN_CHUNK)
#define RSTART    2    // phase-1 ball radius = margin(RSTART)
#define RESC      4    // escalation ball radius = margin(RESC)
#define SEL_CAP  1024  // appended-key list (u64, 8KB)

// ---------------- workspace layout (bytes) ----------------
#define OFF_CNT     ((size_t)0)
#define OFF_OFFS    (OFF_CNT    + (size_t)TOTC*4)
#define OFF_CELLID  (OFF_OFFS   + (size_t)TOTC*4)
#define OFF_RANK    (OFF_CELLID + (size_t)NTOT*4)
#define OFF_SPOS    (OFF_RANK   + (size_t)NTOT*4)          // float4 * NTOT (w = origidx bits)
#define OFF_KNN     (OFF_SPOS   + (size_t)NTOT*16)         // int * NTOT*16
#define OFF_SPATIAL (OFF_KNN    + (size_t)NTOT*16*4)       // [B,4,N]
#define OFF_XT      (OFF_SPATIAL+ (size_t)NB*4*NPTS*4)     // [B,N,128]
#define OFF_MD      (OFF_XT     + (size_t)NB*128*NPTS*4)   // [B,128,N]
#define OFF_S1      (OFF_MD     + (size_t)NB*128*NPTS*4)   // [B,32,N]
#define OFF_SF      (OFF_S1     + (size_t)NB*32*NPTS*4)    // [B,64,N]
#define OFF_Y1      (OFF_SF     + (size_t)NB*64*NPTS*4)    // [B,128,N]
#define OFF_Y2      (OFF_Y1     + (size_t)NB*128*NPTS*4)   // [B,128,N]
#define OFF_A1      (OFF_Y2     + (size_t)NB*128*NPTS*4)   // [B,64,N]
#define OFF_SC      (OFF_A1     + (size_t)NB*64*NPTS*4)    // 1088 floats
#define OFF_BSUM    (OFF_SC     + (size_t)1088*4)          // NBLK_SCAN ints
#define OFF_BPRE    (OFF_BSUM   + (size_t)NBLK_SCAN*4)     // NBLK_SCAN ints
#define OFF_RNG     (((OFF_BPRE + (size_t)NBLK_SCAN*4) + 15) & ~(size_t)15)  // int2 * TOTC

// Replicate reference arithmetic exactly (no fma contraction).
static __device__ __forceinline__ float sumsq3(float x, float y, float z) {
    return __fadd_rn(__fadd_rn(__fmul_rn(x, x), __fmul_rn(y, y)), __fmul_rn(z, z));
}
static __device__ __forceinline__ float pdist4(float qx, float qy, float qz, float qxx,
                                               float px, float py, float pz) {
    float pxx = sumsq3(px, py, pz);
    float dot = __fadd_rn(__fadd_rn(__fmul_rn(qx, px), __fmul_rn(qy, py)), __fmul_rn(qz, pz));
    return __fsub_rn(__fadd_rn(qxx, pxx), __fadd_rn(dot, dot));
}
// monotone unsigned key for float (handles tiny negative self-distance)
static __device__ __forceinline__ unsigned fkey(float f) {
    unsigned b = __float_as_uint(f);
    return b ^ ((unsigned)(((int)b) >> 31) | 0x80000000u);
}
static __device__ __forceinline__ unsigned long long shflx64(unsigned long long v, int m) {
    unsigned lo = __shfl_xor((unsigned)v, m, 64);
    unsigned hi = __shfl_xor((unsigned)(v >> 32), m, 64);
    return ((unsigned long long)hi << 32) | lo;
}
// inclusive wave prefix-sum (all 64 lanes active)
static __device__ __forceinline__ int wave_scan_incl(int v, int lane) {
    #pragma unroll
    for (int d = 1; d < 64; d <<= 1) {
        int u = __shfl_up(v, d, 64);
        v += (lane >= d) ? u : 0;
    }
    return v;
}
// key threshold from margin m (>0): all keys strictly below are certified-complete
static __device__ __forceinline__ unsigned long long tkmake(float m) {
    return ((unsigned long long)(fkey(__fsub_rn(__fmul_rn(m, m), 1e-4f)) + 1u)) << 27;
}

// ---------------- grid build ----------------
__global__ void cell_build(const float* __restrict__ xyz, int* __restrict__ cnt,
                           int* __restrict__ cellid, int* __restrict__ rank) {
    int t = blockIdx.x * 256 + threadIdx.x;
    if (t >= NTOT) return;
    const float* p = xyz + (size_t)t * 3;
    float x = p[0], y = p[1], z = p[2];
    int cx = min(GD - 1, max(0, (int)floorf((x - ORGN) * INVH)));
    int cy = min(GD - 1, max(0, (int)floorf((y - ORGN) * INVH)));
    int cz = min(GD - 1, max(0, (int)floorf((z - ORGN) * INVH)));
    int gcell = (t >> 13) * NCELL + (cz * GD + cy) * GD + cx;
    rank[t] = atomicAdd(&cnt[gcell], 1);
    cellid[t] = gcell;
}

// -------- hierarchical exclusive scan of cnt[TOTC] -> offs[TOTC] (+rng int2) --------
__global__ __launch_bounds__(256) void scan_sums(const int* __restrict__ cnt, int* __restrict__ bsum) {
    __shared__ int red[256];
    int blk = blockIdx.x, t = threadIdx.x;
    int i0 = blk * SCAN_CHUNK + t * 4;
    int s = 0;
    if (i0 + 3 < TOTC) {
        int4 v = *(const int4*)(cnt + i0);
        s = v.x + v.y + v.z + v.w;
    } else {
        for (int j = 0; j < 4; ++j) if (i0 + j < TOTC) s += cnt[i0 + j];
    }
    red[t] = s;
    __syncthreads();
    for (int d = 128; d > 0; d >>= 1) {
        if (t < d) red[t] += red[t + d];
        __syncthreads();
    }
    if (t == 0) bsum[blk] = red[0];
}

__global__ __launch_bounds__(512) void scan_top(const int* __restrict__ bsum, int* __restrict__ bpre) {
    __shared__ int ps[512];
    int t = threadIdx.x;
    int v = (t < NBLK_SCAN) ? bsum[t] : 0;
    ps[t] = v;
    __syncthreads();
    for (int d = 1; d < 512; d <<= 1) {
        int u = 0;
        if (t >= d) u = ps[t - d];
        __syncthreads();
        ps[t] += u;
        __syncthreads();
    }
    if (t < NBLK_SCAN) bpre[t] = ps[t] - v;   // exclusive
}

__global__ __launch_bounds__(256) void scan_write(const int* __restrict__ cnt, const int* __restrict__ bpre,
                                                  int* __restrict__ offs, int2* __restrict__ rng) {
    __shared__ int ps[256];
    int blk = blockIdx.x, t = threadIdx.x;
    int i0 = blk * SCAN_CHUNK + t * 4;
    int a = 0, b = 0, c = 0, d = 0;
    if (i0 + 3 < TOTC) {
        int4 v = *(const int4*)(cnt + i0);
        a = v.x; b = v.y; c = v.z; d = v.w;
    } else {
        if (i0 + 0 < TOTC) a = cnt[i0 + 0];
        if (i0 + 1 < TOTC) b = cnt[i0 + 1];
        if (i0 + 2 < TOTC) c = cnt[i0 + 2];
        if (i0 + 3 < TOTC) d = cnt[i0 + 3];
    }
    int s = a + b + c + d;
    ps[t] = s;
    __syncthreads();
    for (int dd = 1; dd < 256; dd <<= 1) {
        int u = 0;
        if (t >= dd) u = ps[t - dd];
        __syncthreads();
        ps[t] += u;
        __syncthreads();
    }
    int base = bpre[blk] + ps[t] - s;
    if (i0 + 3 < TOTC) {
        offs[i0 + 0] = base;
        offs[i0 + 1] = base + a;
        offs[i0 + 2] = base + a + b;
        offs[i0 + 3] = base + a + b + c;
        *(int4*)(rng + i0)     = make_int4(base, base + a, base + a, base + a + b);
        *(int4*)(rng + i0 + 2) = make_int4(base + a + b, base + a + b + c,
                                           base + a + b + c, base + s);
    } else {
        if (i0 + 0 < TOTC) { offs[i0 + 0] = base;             rng[i0 + 0] = make_int2(base, base + a); }
        if (i0 + 1 < TOTC) { offs[i0 + 1] = base + a;         rng[i0 + 1] = make_int2(base + a, base + a + b); }
        if (i0 + 2 < TOTC) { offs[i0 + 2] = base + a + b;     rng[i0 + 2] = make_int2(base + a + b, base + a + b + c); }
        if (i0 + 3 < TOTC) { offs[i0 + 3] = base + a + b + c; rng[i0 + 3] = make_int2(base + a + b + c, base + s); }
    }
}

__global__ void scatter_k(const float* __restrict__ xyz, const int* __restrict__ cellid,
                          const int* __restrict__ rank, const int* __restrict__ offs,
                          float4* __restrict__ spos) {
    int t = blockIdx.x * 256 + threadIdx.x;
    if (t >= NTOT) return;
    const float* p = xyz + (size_t)t * 3;
    float x = p[0], y = p[1], z = p[2];
    int pos = offs[cellid[t]] + rank[t];
    spos[pos] = make_float4(x, y, z, __int_as_float(t & (NPTS - 1)));
}

// ---------------- exact KNN: one wave per query ----------------
// R11: (a) ball-pruned rows — per (dz,dy) row scan only x-cells intersecting
// ball(mfin) (corner cells of the old box were 0.87 away vs ~0.45 needed);
// (b) tight append threshold margin(RSTART) — stop condition becomes tot>=16;
// escalation RESETS and rescans at margin(RESC) (self-contained certificate);
// (c) register binary-search expansion (6-step shfl lower_bound over per-lane
// run prefix) replaces the LDS lst (kills the 206K bank conflicts + the
// write->wait->read->gather chain). Selection: rank-count over certified-
// complete sel (R8/R10-proven). Brute tail: R10's two-pass ladder verbatim.
__global__ __launch_bounds__(64) void knn_kernel(const float4* __restrict__ spos,
                                                 const int2* __restrict__ rng,
                                                 int* __restrict__ knn,
                                                 float* __restrict__ spatial) {
    __shared__ __align__(16) unsigned long long sel[SEL_CAP];  // 8 KB
    __shared__ __align__(16) unsigned long long sel2[512];     // 4 KB
    int lane = threadIdx.x;
    int bid  = blockIdx.x;
    int s = (bid & 7) * (NTOT / 8) + (bid >> 3);   // XCD-chunked swizzle
    float4 q = spos[s];
    float qx = q.x, qy = q.y, qz = q.z;
    float qxx = sumsq3(qx, qy, qz);
    int b  = s >> 13;
    int nq = __float_as_int(q.w);
    int cx = min(GD - 1, max(0, (int)floorf((qx - ORGN) * INVH)));
    int cy = min(GD - 1, max(0, (int)floorf((qy - ORGN) * INVH)));
    int cz = min(GD - 1, max(0, (int)floorf((qz - ORGN) * INVH)));
    const int2* rg = rng + b * NCELL;

    float mlx = qx - (ORGN + (float)cx * HCELL);
    float mhx = (ORGN + (float)(cx + 1) * HCELL) - qx;
    float mly = qy - (ORGN + (float)cy * HCELL);
    float mhy = (ORGN + (float)(cy + 1) * HCELL) - qy;
    float mlz = qz - (ORGN + (float)cz * HCELL);
    float mhz = (ORGN + (float)(cz + 1) * HCELL) - qz;
    float margin0 = fminf(fminf(fminf(mlx, mhx), fminf(mly, mhy)), fminf(mlz, mhz));

    int tot = 0, ovf = 0;

    // scan all cells intersecting ball(mfin); append keys < tkfin to sel.
    auto scan_ball = [&](int RB, float mfin, unsigned long long tkfin) {
        if (mfin <= 0.f) return;
        float mfin2 = mfin * mfin;
        int L = 2 * RB + 1, nrows = L * L;
        for (int r0 = 0; r0 < nrows; r0 += 64) {
            int nr = min(64, nrows - r0);
            int rr = r0 + lane;
            int num = 0, start = 0;
            if (rr < nrows) {
                int dzr = rr / L - RB, dyr = rr % L - RB;
                int zc = cz + dzr, yc = cy + dyr;
                if ((unsigned)zc < GD && (unsigned)yc < GD) {
                    float ylo = ORGN + (float)yc * HCELL;
                    float zlo = ORGN + (float)zc * HCELL;
                    float dyl = fmaxf(fmaxf(ylo - qy, qy - (ylo + HCELL)), 0.f);
                    float dzl = fmaxf(fmaxf(zlo - qz, qz - (zlo + HCELL)), 0.f);
                    float rem = mfin2 - dyl * dyl - dzl * dzl;
                    if (rem > -1e-4f) {
                        float xh = sqrtf(fmaxf(rem, 0.f)) + 1e-3f;  // cushion: include boundary cells
                        int xlo = max(0, (int)floorf((qx - xh - ORGN) * INVH));
                        int xhi = min(GD - 1, (int)floorf((qx + xh - ORGN) * INVH));
                        if (xlo <= xhi) {
                            int rowb = (zc * GD + yc) * GD;
                            start = rg[rowb + xlo].x;
                            num   = rg[rowb + xhi].y - start;
                        }
                    }
                }
            }
            int inc = wave_scan_incl(num, lane);
            int ctot = __shfl(inc, 63, 64);
            if (ctot == 0) continue;
            int excl = inc - num;
            // expand candidate index -> slot via 6-step shfl lower_bound, then gather
            auto eg = [&](int base, int& sv, float4& pv, bool& vld) {
                int t = base + lane;
                vld = t < ctot;
                int tc = vld ? t : (ctot - 1);
                int lo = 0, hi = nr - 1;
                #pragma unroll
                for (int st = 0; st < 6; ++st) {
                    int mid = (lo + hi + 1) >> 1;
                    int e = __shfl(excl, mid, 64);
                    bool g = (e <= tc);
                    lo = g ? mid : lo;
                    hi = g ? hi : (mid - 1);
                }
                sv = __shfl(start, lo, 64) + (tc - __shfl(excl, lo, 64));
                pv = spos[sv];
            };
            int s0; float4 p0; bool v0;
            eg(0, s0, p0, v0);
            for (int base = 0; base < ctot; base += 64) {
                int s1 = 0; float4 p1 = p0; bool v1 = false;
                if (base + 64 < ctot) eg(base + 64, s1, p1, v1);   // prefetch next chunk
                float d = pdist4(qx, qy, qz, qxx, p0.x, p0.y, p0.z);
                unsigned long long key = ((unsigned long long)fkey(d) << 27)
                                       | ((unsigned long long)(unsigned)__float_as_int(p0.w) << 14)
                                       | (unsigned)s0;
                bool pass = v0 && (key < tkfin);
                unsigned long long mk = __ballot(pass);
                int cnum = (int)__popcll(mk);
                if (tot + cnum > SEL_CAP) { ovf = 1; return; }
                if (pass) sel[tot + (int)__popcll(mk & ((1ULL << lane) - 1ULL))] = key;
                tot += cnum;
                s0 = s1; p0 = p1; v0 = v1;
            }
        }
    };

    auto count_below = [&](unsigned long long tk) {
        int c = 0;
        for (int t0 = 0; t0 < tot; t0 += 64) {
            int tt = t0 + lane;
            if (tt < tot) c += (sel[tt] < tk) ? 1 : 0;
        }
        for (int o = 32; o > 0; o >>= 1) c += __shfl_xor(c, o, 64);
        return c;
    };

    // ---- phase 1: ball(margin(RSTART)) ----
    float mfin1 = margin0 + (float)RSTART * HCELL;
    unsigned long long tkf1 = (mfin1 > 0.f) ? tkmake(mfin1) : 0ULL;
    if (tkf1) scan_ball(RSTART, mfin1, tkf1);

    unsigned long long tkey_sel = ~0ULL;
    int csel = 0;
    bool have = false;
    if (!ovf && tot >= 16) {
        float mA = margin0 + 1.0f * HCELL;
        if (mA > 0.f) {
            unsigned long long tkA = tkmake(mA);
            int cA = count_below(tkA);
            if (cA >= 16) { tkey_sel = tkA; csel = cA; have = true; }
        }
        if (!have) { tkey_sel = ~0ULL; csel = tot; have = true; }   // all of sel (< margin(RSTART))
    }
    if (!have && !ovf) {
        // ---- escalation: reset + rescan ball(margin(RESC)) ----
        tot = 0;
        float mfin4 = margin0 + (float)RESC * HCELL;
        unsigned long long tkf4 = (mfin4 > 0.f) ? tkmake(mfin4) : 0ULL;
        if (tkf4) scan_ball(RESC, mfin4, tkf4);
        if (!ovf && tot >= 16) {
            float mB = margin0 + (float)(RESC - 1) * HCELL;
            if (mB > 0.f) {
                unsigned long long tkB = tkmake(mB);
                int cB = count_below(tkB);
                if (cB >= 16) { tkey_sel = tkB; csel = cB; have = true; }
            }
            if (!have) { tkey_sel = ~0ULL; csel = tot; have = true; }
        }
    }

    if (!have) {
        // ---- two-pass ladder brute over all NPTS of this batch (R10-proven) ----
        const float LADR[16] = {0.35f, 0.4725f, 0.637875f, 0.86113125f,
                                1.1625272f, 1.5694117f, 2.1187058f, 2.8602529f,
                                3.8613414f, 5.2128109f, 7.0372947f, 9.5003478f,
                                12.825470f, 17.314384f, 23.374418f, 31.555464f};
        int sbase = b << 13;
        int cc[16];
        #pragma unroll
        for (int k = 0; k < 16; ++k) cc[k] = 0;
        for (int i0 = 0; i0 < NPTS; i0 += 64) {
            float4 p = spos[sbase + i0 + lane];
            float d = pdist4(qx, qy, qz, qxx, p.x, p.y, p.z);
            #pragma unroll
            for (int k = 0; k < 16; ++k) cc[k] += (d < LADR[k] * LADR[k]) ? 1 : 0;
        }
        #pragma unroll
        for (int k = 0; k < 16; ++k)
            for (int o = 32; o > 0; o >>= 1) cc[k] += __shfl_xor(cc[k], o, 64);
        float Tq = LADR[15] * LADR[15]; int cL = cc[15];
        #pragma unroll
        for (int k = 14; k >= 0; --k) if (cc[k] >= 16) { Tq = LADR[k] * LADR[k]; cL = cc[k]; }
        if (cL <= SEL_CAP) {
            tot = 0;
            for (int i0 = 0; i0 < NPTS; i0 += 64) {
                int idx = sbase + i0 + lane;
                float4 p = spos[idx];
                float d = pdist4(qx, qy, qz, qxx, p.x, p.y, p.z);
                bool pass = (d < Tq);
                unsigned long long key = ((unsigned long long)fkey(d) << 27)
                                       | ((unsigned long long)(unsigned)__float_as_int(p.w) << 14)
                                       | (unsigned)idx;
                unsigned long long mk = __ballot(pass);
                if (pass) sel[tot + (int)__popcll(mk & ((1ULL << lane) - 1ULL))] = key;
                tot += (int)__popcll(mk);
            }
            tkey_sel = ~0ULL;
            csel = tot;
        } else {
            // ultra-rare capacity fallback: per-lane top16 in sel region + 16-round extract
            unsigned long long* mybuf = sel + lane;   // element j at [j*64]
            unsigned long long minkey = ~0ULL, maxkey = 0;
            int nbuf = 0;
            for (int i = lane; i < NPTS; i += 64) {
                float4 p = spos[sbase + i];
                float d = pdist4(qx, qy, qz, qxx, p.x, p.y, p.z);
                unsigned long long key = ((unsigned long long)fkey(d) << 27)
                                       | ((unsigned long long)(unsigned)__float_as_int(p.w) << 14)
                                       | (unsigned)(sbase + i);
                if (nbuf < 16) {
                    mybuf[(size_t)nbuf * 64] = key;
                    ++nbuf;
                    minkey = (key < minkey) ? key : minkey;
                    maxkey = (key > maxkey) ? key : maxkey;
                } else if (key < maxkey) {
                    unsigned long long vmax = 0, v2 = 0;
                    int pmax = 0;
                    #pragma unroll
                    for (int j = 0; j < 16; ++j) {
                        unsigned long long v = mybuf[(size_t)j * 64];
                        if (v > vmax) { v2 = vmax; vmax = v; pmax = j; }
                        else if (v > v2) { v2 = v; }
                    }
                    mybuf[(size_t)pmax * 64] = key;
                    maxkey = (key > v2) ? key : v2;
                    minkey = (key < minkey) ? key : minkey;
                }
            }
            unsigned long long keep = ~0ULL;
            for (int k = 0; k < 16; ++k) {
                unsigned long long m = minkey;
                for (int o = 32; o > 0; o >>= 1) {
                    unsigned long long pv = shflx64(m, o);
                    m = (pv < m) ? pv : m;
                }
                unsigned long long bal = __ballot(minkey == m);
                int wl = __ffsll((long long)bal) - 1;
                if (lane == wl) {
                    int pos = 0;
                    for (int j = 0; j < nbuf; ++j) if (mybuf[(size_t)j * 64] == m) pos = j;
                    --nbuf;
                    mybuf[(size_t)pos * 64] = mybuf[(size_t)nbuf * 64];
                    unsigned long long nm = ~0ULL;
                    for (int j = 0; j < nbuf; ++j) {
                        unsigned long long v = mybuf[(size_t)j * 64];
                        nm = (v < nm) ? v : nm;
                    }
                    minkey = nm;
                }
                if (lane == k) keep = m;
            }
            float rx = 0.f, ry = 0.f, rz = 0.f, rd = 0.f;
            if (lane < 16) {
                int sp = (int)(keep & 0x3FFFu);
                int oi = (int)((keep >> 14) & 0x1FFFu);
                float4 p = spos[sp];
                rx = p.x - qx; ry = p.y - qy; rz = p.z - qz;
                rd = sqrtf(__fadd_rn(__fadd_rn(__fmul_rn(rx, rx), __fmul_rn(ry, ry)), __fmul_rn(rz, rz)));
                knn[(((size_t)b << 13) + nq) * 16 + lane] = oi;
            }
            for (int o = 8; o > 0; o >>= 1) {
                rx += __shfl_xor(rx, o, 64);
                ry += __shfl_xor(ry, o, 64);
                rz += __shfl_xor(rz, o, 64);
                rd += __shfl_xor(rd, o, 64);
            }
            if (lane == 0) {
                const float inv16 = 0.0625f;
                spatial[((size_t)b * 4 + 0) * NPTS + nq] = rx * inv16;
                spatial[((size_t)b * 4 + 1) * NPTS + nq] = ry * inv16;
                spatial[((size_t)b * 4 + 2) * NPTS + nq] = rz * inv16;
                spatial[((size_t)b * 4 + 3) * NPTS + nq] = rd * inv16;
            }
            return;
        }
    }

    // -------- shared selection: compact keys < tkey_sel, then rank-count --------
    const unsigned long long* src = sel;
    int m = tot;
    if (tkey_sel != ~0ULL && csel <= 512) {
        int w = 0;
        for (int t0 = 0; t0 < tot; t0 += 64) {
            int tt = t0 + lane;
            unsigned long long v = (tt < tot) ? sel[tt] : ~0ULL;
            bool pass = (tt < tot) && (v < tkey_sel);
            unsigned long long mk = __ballot(pass);
            if (pass) sel2[w + (int)__popcll(mk & ((1ULL << lane) - 1ULL))] = v;
            w += (int)__popcll(mk);
        }
        asm volatile("s_waitcnt lgkmcnt(0)" ::: "memory");
        __builtin_amdgcn_sched_barrier(0);
        src = sel2; m = w;
        tkey_sel = ~0ULL;   // compacted list is fully qualified
    }
    float rxs = 0.f, rys = 0.f, rzs = 0.f, rds = 0.f;
    for (int t0 = 0; t0 < m; t0 += 64) {
        int tt = t0 + lane;
        if (tt < m) {
            unsigned long long kt = src[tt];
            if (kt < tkey_sel) {
                int rr = 0;
                for (int j = 0; j < m; ++j) rr += (src[j] < kt) ? 1 : 0;   // broadcast reads
                if (rr < 16) {
                    int sp = (int)(kt & 0x3FFFu);
                    int oi = (int)((kt >> 14) & 0x1FFFu);
                    float4 p = spos[sp];
                    float dx = p.x - qx, dy = p.y - qy, dz = p.z - qz;
                    float dl = sqrtf(__fadd_rn(__fadd_rn(__fmul_rn(dx, dx), __fmul_rn(dy, dy)), __fmul_rn(dz, dz)));
                    knn[(((size_t)b << 13) + nq) * 16 + rr] = oi;
                    rxs += dx; rys += dy; rzs += dz; rds += dl;
                }
            }
        }
    }
    for (int o = 32; o > 0; o >>= 1) {
        rxs += __shfl_xor(rxs, o, 64);
        rys += __shfl_xor(rys, o, 64);
        rzs += __shfl_xor(rzs, o, 64);
        rds += __shfl_xor(rds, o, 64);
    }
    if (lane == 0) {
        const float inv16 = 0.0625f;
        spatial[((size_t)b * 4 + 0) * NPTS + nq] = rxs * inv16;
        spatial[((size_t)b * 4 + 1) * NPTS + nq] = rys * inv16;
        spatial[((size_t)b * 4 + 2) * NPTS + nq] = rzs * inv16;
        spatial[((size_t)b * 4 + 3) * NPTS + nq] = rds * inv16;
    }
}

// ---------------- x[B,C,N] -> xT[B,N,C] ----------------
__global__ void transpose_k(const float* __restrict__ x, float* __restrict__ xT) {
    __shared__ float tl[32][33];
    int b = blockIdx.z;
    int n0 = blockIdx.x * 32, c0 = blockIdx.y * 32;
    int tx = threadIdx.x, ty = threadIdx.y;
    const float* xb = x + (size_t)b * 128 * NN;
    float* xtb = xT + (size_t)b * NN * 128;
    for (int i = 0; i < 32; i += 8) tl[ty + i][tx] = xb[(size_t)(c0 + ty + i) * NN + n0 + tx];
    __syncthreads();
    for (int i = 0; i < 32; i += 8) xtb[(size_t)(n0 + ty + i) * 128 + c0 + tx] = tl[tx][ty + i];
}

// ---------------- max_k(x[:,idx_k]) - x  -> md[B,128,N] ----------------
__global__ __launch_bounds__(256) void md_k(const float* __restrict__ xT,
                                            const int* __restrict__ knn,
                                            float* __restrict__ md) {
    __shared__ int ki[8][16];
    __shared__ float smd[8][132];
    int b = blockIdx.y;
    int n0 = blockIdx.x * 8;
    int tid = threadIdx.x;
    if (tid < 128) ki[tid >> 4][tid & 15] = knn[(((size_t)b << 13) + n0 + (tid >> 4)) * 16 + (tid & 15)];
    __syncthreads();
    int nl = tid >> 5;
    int c4 = (tid & 31) * 4;
    const float* xb = xT + (size_t)b * NPTS * 128;
    float4 m = make_float4(-3.0e38f, -3.0e38f, -3.0e38f, -3.0e38f);
    #pragma unroll
    for (int k = 0; k < 16; ++k) {
        const float4 g = *(const float4*)(xb + (size_t)ki[nl][k] * 128 + c4);
        m.x = fmaxf(m.x, g.x); m.y = fmaxf(m.y, g.y); m.z = fmaxf(m.z, g.z); m.w = fmaxf(m.w, g.w);
    }
    const float4 own = *(const float4*)(xb + (size_t)(n0 + nl) * 128 + c4);
    m.x -= own.x; m.y -= own.y; m.z -= own.z; m.w -= own.w;
    *(float4*)(&smd[nl][c4]) = m;
    __syncthreads();
    for (int r = 0; r < 4; ++r) {
        int c = (tid >> 3) + 32 * r;
        int n2 = tid & 7;
        md[((size_t)b * 128 + c) * NN + n0 + n2] = smd[n2][c];
    }
}

// ---------------- fold conv-bias + BN into per-channel scale/shift ----------------
__global__ void prep_k(const float* bb1, const float* g1, const float* be1, const float* m1, const float* v1,
                       const float* bb2, const float* g2, const float* be2, const float* m2, const float* v2,
                       const float* sb1, const float* gs,  const float* bes, const float* ms, const float* vs,
                       const float* sb2,
                       const float* ab1, const float* ga,  const float* bea, const float* ma, const float* va,
                       const float* ab2, float* sc) {
    int t = threadIdx.x;
    if (t < 128) {
        float i1 = g1[t] / sqrtf(v1[t] + 1e-5f);
        sc[t] = i1;        sc[128 + t] = bb1[t] * i1 + be1[t] - m1[t] * i1;
        float i2 = g2[t] / sqrtf(v2[t] + 1e-5f);
        sc[256 + t] = i2;  sc[384 + t] = bb2[t] * i2 + be2[t] - m2[t] * i2;
        sc[832 + t] = 1.0f; sc[960 + t] = ab2[t];
    }
    if (t < 32) {
        float is = gs[t] / sqrtf(vs[t] + 1e-5f);
        sc[512 + t] = is;  sc[544 + t] = sb1[t] * is + bes[t] - ms[t] * is;
    }
    if (t < 64) {
        sc[576 + t] = 1.0f; sc[640 + t] = sb2[t];
        float ia = ga[t] / sqrtf(va[t] + 1e-5f);
        sc[704 + t] = ia;  sc[768 + t] = ab1[t] * ia + bea[t] - ma[t] * ia;
    }
}

// ---------------- generic 1x1-conv (+folded BN, activation) ----------------
// ACT: 0=none, 1=relu, 2=sigmoid + fused "dout = x + y2*attn"
template <int O, int K, int TILE_N, int SPLIT, int ACT>
__global__ __launch_bounds__(256) void conv_bn(const float* __restrict__ srcA,
                                               const float* __restrict__ srcB,
                                               const float* __restrict__ W,
                                               const float* __restrict__ scale,
                                               const float* __restrict__ shift,
                                               float* __restrict__ out,
                                               const float* __restrict__ resx,
                                               const float* __restrict__ y2,
                                               float* __restrict__ dout) {
    constexpr int KC  = (K < 64) ? K : 64;
    constexpr int NT4 = TILE_N / 4;
    constexpr int O4  = O / 4;
    static_assert(NT4 * O4 == 256, "thread mapping");
    __shared__ float wT[KC][O + 4];
    __shared__ float inT[KC][TILE_N];
    int tid = threadIdx.x;
    int b = blockIdx.z;
    int n0 = blockIdx.x * TILE_N;
    int n_thr = tid % NT4;          // n fastest -> coalesced stores
    int o_thr = tid / NT4;
    float acc[4][4] = {{0.f, 0.f, 0.f, 0.f}, {0.f, 0.f, 0.f, 0.f}, {0.f, 0.f, 0.f, 0.f}, {0.f, 0.f, 0.f, 0.f}};

    for (int k0 = 0; k0 < K; k0 += KC) {
        for (int idx = tid; idx < KC * O; idx += 256) {
            int cc = idx % KC;
            int o  = idx / KC;
            wT[cc][o] = W[(size_t)o * K + k0 + cc];
        }
        for (int idx = tid; idx < KC * NT4; idx += 256) {
            int cc = idx / NT4;
            int nf = idx % NT4;
            int cg = k0 + cc;
            const float* src = (cg < SPLIT)
                ? (srcA + ((size_t)b * SPLIT + cg) * NN)
                : (srcB + ((size_t)b * (K - SPLIT) + (cg - SPLIT)) * NN);
            *(float4*)(&inT[cc][nf * 4]) = *(const float4*)(src + n0 + nf * 4);
        }
        __syncthreads();
        #pragma unroll 8
        for (int c = 0; c < KC; ++c) {
            float4 wv = *(const float4*)(&wT[c][o_thr * 4]);
            float4 iv = *(const float4*)(&inT[c][n_thr * 4]);
            acc[0][0] = fmaf(wv.x, iv.x, acc[0][0]); acc[0][1] = fmaf(wv.x, iv.y, acc[0][1]);
            acc[0][2] = fmaf(wv.x, iv.z, acc[0][2]); acc[0][3] = fmaf(wv.x, iv.w, acc[0][3]);
            acc[1][0] = fmaf(wv.y, iv.x, acc[1][0]); acc[1][1] = fmaf(wv.y, iv.y, acc[1][1]);
            acc[1][2] = fmaf(wv.y, iv.z, acc[1][2]); acc[1][3] = fmaf(wv.y, iv.w, acc[1][3]);
            acc[2][0] = fmaf(wv.z, iv.x, acc[2][0]); acc[2][1] = fmaf(wv.z, iv.y, acc[2][1]);
            acc[2][2] = fmaf(wv.z, iv.z, acc[2][2]); acc[2][3] = fmaf(wv.z, iv.w, acc[2][3]);
            acc[3][0] = fmaf(wv.w, iv.x, acc[3][0]); acc[3][1] = fmaf(wv.w, iv.y, acc[3][1]);
            acc[3][2] = fmaf(wv.w, iv.z, acc[3][2]); acc[3][3] = fmaf(wv.w, iv.w, acc[3][3]);
        }
        __syncthreads();
    }
    #pragma unroll
    for (int j = 0; j < 4; ++j) {
        int o = o_thr * 4 + j;
        float scv = scale[o], shv = shift[o];
        float4 v;
        v.x = fmaf(acc[j][0], scv, shv);
        v.y = fmaf(acc[j][1], scv, shv);
        v.z = fmaf(acc[j][2], scv, shv);
        v.w = fmaf(acc[j][3], scv, shv);
        size_t obase = ((size_t)b * O + o) * NN + n0 + n_thr * 4;
        if (ACT == 1) {
            v.x = fmaxf(v.x, 0.f); v.y = fmaxf(v.y, 0.f); v.z = fmaxf(v.z, 0.f); v.w = fmaxf(v.w, 0.f);
            *(float4*)(out + obase) = v;
        } else if (ACT == 2) {
            float4 xr = *(const float4*)(resx + obase);
            float4 yr = *(const float4*)(y2 + obase);
            v.x = xr.x + yr.x / (1.f + __expf(-v.x));
            v.y = xr.y + yr.y / (1.f + __expf(-v.y));
            v.z = xr.z + yr.z / (1.f + __expf(-v.z));
            v.w = xr.w + yr.w / (1.f + __expf(-v.w));
            *(float4*)(dout + obase) = v;
        } else {
            *(float4*)(out + obase) = v;
        }
    }
}

extern "C" void kernel_launch(void* const* d_in, const int* in_sizes, int n_in,
                              void* d_out, int out_size, void* d_ws, size_t ws_size,
                              hipStream_t stream) {
    (void)in_sizes; (void)n_in; (void)out_size; (void)ws_size;
    const float* x    = (const float*)d_in[0];
    const float* xyz  = (const float*)d_in[1];
    const float* bw1  = (const float*)d_in[2];
    const float* bb1  = (const float*)d_in[3];
    const float* bn1g = (const float*)d_in[4];
    const float* bn1b = (const float*)d_in[5];
    const float* bn1m = (const float*)d_in[6];
    const float* bn1v = (const float*)d_in[7];
    const float* bw2  = (const float*)d_in[8];
    const float* bb2  = (const float*)d_in[9];
    const float* bn2g = (const float*)d_in[10];
    const float* bn2b = (const float*)d_in[11];
    const float* bn2m = (const float*)d_in[12];
    const float* bn2v = (const float*)d_in[13];
    const float* sw1  = (const float*)d_in[14];
    const float* sb1  = (const float*)d_in[15];
    const float* sbng = (const float*)d_in[16];
    const float* sbnb = (const float*)d_in[17];
    const float* sbnm = (const float*)d_in[18];
    const float* sbnv = (const float*)d_in[19];
    const float* sw2  = (const float*)d_in[20];
    const float* sb2  = (const float*)d_in[21];
    const float* aw1  = (const float*)d_in[22];
    const float* ab1  = (const float*)d_in[23];
    const float* abng = (const float*)d_in[24];
    const float* abnb = (const float*)d_in[25];
    const float* abnm = (const float*)d_in[26];
    const float* abnv = (const float*)d_in[27];
    const float* aw2  = (const float*)d_in[28];
    const float* ab2  = (const float*)d_in[29];

    char* ws = (char*)d_ws;
    int*    cnt    = (int*)(ws + OFF_CNT);
    int*    offs   = (int*)(ws + OFF_OFFS);
    int*    cellid = (int*)(ws + OFF_CELLID);
    int*    rank   = (int*)(ws + OFF_RANK);
    float4* spos   = (float4*)(ws + OFF_SPOS);
    int*    knn    = (int*)(ws + OFF_KNN);
    float*  spat   = (float*)(ws + OFF_SPATIAL);
    float*  xT     = (float*)(ws + OFF_XT);
    float*  md     = (float*)(ws + OFF_MD);
    float*  s1b    = (float*)(ws + OFF_S1);
    float*  sfb    = (float*)(ws + OFF_SF);
    float*  y1b    = (float*)(ws + OFF_Y1);
    float*  y2b    = (float*)(ws + OFF_Y2);
    float*  a1b    = (float*)(ws + OFF_A1);
    float*  sc     = (float*)(ws + OFF_SC);
    int*    bsum   = (int*)(ws + OFF_BSUM);
    int*    bpre   = (int*)(ws + OFF_BPRE);
    int2*   rng    = (int2*)(ws + OFF_RNG);
    float*  dout   = (float*)d_out;

    hipMemsetAsync(cnt, 0, (size_t)TOTC * 4, stream);
    cell_build<<<dim3((NTOT + 255) / 256), 256, 0, stream>>>(xyz, cnt, cellid, rank);
    scan_sums<<<dim3(NBLK_SCAN), 256, 0, stream>>>(cnt, bsum);
    scan_top<<<dim3(1), 512, 0, stream>>>(bsum, bpre);
    scan_write<<<dim3(NBLK_SCAN), 256, 0, stream>>>(cnt, bpre, offs, rng);
    scatter_k<<<dim3((NTOT + 255) / 256), 256, 0, stream>>>(xyz, cellid, rank, offs, spos);
    knn_kernel<<<dim3(NTOT), 64, 0, stream>>>(spos, rng, knn, spat);
    transpose_k<<<dim3(NPTS / 32, 128 / 32, NB), dim3(32, 8), 0, stream>>>(x, xT);
    md_k<<<dim3(NPTS / 8, NB), 256, 0, stream>>>(xT, knn, md);
    prep_k<<<1, 128, 0, stream>>>(bb1, bn1g, bn1b, bn1m, bn1v,
                                  bb2, bn2g, bn2b, bn2m, bn2v,
                                  sb1, sbng, sbnb, sbnm, sbnv,
                                  sb2,
                                  ab1, abng, abnb, abnm, abnv,
                                  ab2, sc);
    // spatial MLP: 4->32 (bn,relu), 32->64
    conv_bn<32, 4, 128, 4, 1><<<dim3(NPTS / 128, 1, NB), 256, 0, stream>>>(
        spat, spat, sw1, sc + 512, sc + 544, s1b, nullptr, nullptr, nullptr);
    conv_bn<64, 32, 64, 32, 0><<<dim3(NPTS / 64, 1, NB), 256, 0, stream>>>(
        s1b, s1b, sw2, sc + 576, sc + 640, sfb, nullptr, nullptr, nullptr);
    // boundary net: [x;md] 256->128 (bn,relu), 128->128 (bn,relu)
    conv_bn<128, 256, 32, 128, 1><<<dim3(NPTS / 32, 1, NB), 256, 0, stream>>>(
        x, md, bw1, sc + 0, sc + 128, y1b, nullptr, nullptr, nullptr);
    conv_bn<128, 128, 32, 128, 1><<<dim3(NPTS / 32, 1, NB), 256, 0, stream>>>(
        y1b, y1b, bw2, sc + 256, sc + 384, y2b, nullptr, nullptr, nullptr);
    // attention: [x;sfeat] 192->64 (bn,relu), 64->128 sigmoid + final fuse
    conv_bn<64, 192, 64, 128, 1><<<dim3(NPTS / 64, 1, NB), 256, 0, stream>>>(
        x, sfb, aw1, sc + 704, sc + 768, a1b, nullptr, nullptr, nullptr);
    conv_bn<128, 64, 32, 64, 2><<<dim3(NPTS / 32, 1, NB), 256, 0, stream>>>(
        a1b, a1b, aw2, sc + 832, sc + 960, dout, x, y2b, dout);
}